// Round 9
// baseline (9334.293 us; speedup 1.0000x reference)
//
#include <hip/hip_runtime.h>
#include <hip/hip_bf16.h>

// ---------------------------------------------------------------------------
// BasicDGCNN forward, MI355X (gfx950). Inputs f32, output f32.
// Output layout (f32, flat): [0,768) vertex | [768,772) num_vertices |
// [772,776) nvs | [776,1800) gfeat | [1800,..) x_concat [4,8192,224].
//
// Round-9: knn_part/knn_merge get __launch_bounds__(...,2) -> VGPR cap 256.
// Evidence for spilling with the old bounds: VGPR_Count=72 vs >=126 live
// values (xi[64]+dl[21]+il[21]), and D=32 vs D=64 knn at IDENTICAL 1.42 ms
// (runtime dominated by a D-independent per-pair spill cost, not the dot).
// ws need = 1,310,720 B (idx; part/gft alias idx after dead) — proven safe.
// ---------------------------------------------------------------------------

#define NPTS 8192
#define BATCH 4
#define KNBR 20

// ===================== KNN phase A: per-split top-21 =======================
// grid (ROWS/128, S); block 128 threads; thread = query point; j-range
// [s*NPTS/S, (s+1)*NPTS/S) staged in TJ-row LDS tiles. dist = xxi+xxj-2dot,
// ascending-c fma chains (bitwise-matched by the merge kernel).
// Candidates (21 u16, dist-sorted, ties j-ascending) -> xcat row scratch.
// launch_bounds(128,2): 2 waves/SIMD min -> <=256 VGPR, NO SPILLS (needs
// ~140 live regs for D=64).
template <int D, int RS, int S, int TJ>
__global__ __launch_bounds__(128, 2) void knn_part(
    const float* feat, float* xcat) {
    __shared__ float xj[TJ * D];
    __shared__ float xxj[TJ];
    const int JC = NPTS / S;

    int gi = blockIdx.x * 128 + threadIdx.x;
    int s  = blockIdx.y;
    int b  = gi >> 13;
    int ib = gi & (NPTS - 1);
    const float* fb = feat + (size_t)b * NPTS * RS;

    float xi[D];
    if (D % 4 == 0) {
        #pragma unroll
        for (int c4 = 0; c4 < D / 4; ++c4) {
            float4 v = *(const float4*)(fb + (size_t)ib * RS + 4 * c4);
            xi[4 * c4] = v.x; xi[4 * c4 + 1] = v.y;
            xi[4 * c4 + 2] = v.z; xi[4 * c4 + 3] = v.w;
        }
    } else {
        #pragma unroll
        for (int c = 0; c < D; ++c) xi[c] = fb[(size_t)ib * RS + c];
    }
    float xxi = 0.f;
    #pragma unroll
    for (int c = 0; c < D; ++c) xxi = fmaf(xi[c], xi[c], xxi);

    float dl[21];
    int   il[21];
    #pragma unroll
    for (int t = 0; t < 21; ++t) { dl[t] = __builtin_inff(); il[t] = 0; }

    for (int j0 = s * JC; j0 < (s + 1) * JC; j0 += TJ) {
        __syncthreads();                       // protect prior-iter reads
        if (D % 4 == 0) {
            for (int e = threadIdx.x; e < TJ * (D / 4); e += 128) {
                int r = e / (D / 4), c4 = e % (D / 4);
                float4 v = *(const float4*)(fb + (size_t)(j0 + r) * RS + 4 * c4);
                *(float4*)(xj + r * D + 4 * c4) = v;
            }
        } else {
            for (int e = threadIdx.x; e < TJ * D; e += 128) {
                int r = e / D, c = e % D;
                xj[e] = fb[(size_t)(j0 + r) * RS + c];
            }
        }
        // norms from GLOBAL (ascending-c fma chain == knn_merge's recompute)
        if (threadIdx.x < TJ) {
            const float* row = fb + (size_t)(j0 + threadIdx.x) * RS;
            float sm = 0.f;
            if (D % 4 == 0) {
                #pragma unroll
                for (int c4 = 0; c4 < D / 4; ++c4) {
                    float4 v = *(const float4*)(row + 4 * c4);
                    sm = fmaf(v.x, v.x, sm); sm = fmaf(v.y, v.y, sm);
                    sm = fmaf(v.z, v.z, sm); sm = fmaf(v.w, v.w, sm);
                }
            } else {
                #pragma unroll
                for (int c = 0; c < D; ++c) sm = fmaf(row[c], row[c], sm);
            }
            xxj[threadIdx.x] = sm;
        }
        __syncthreads();
        for (int jj = 0; jj < TJ; ++jj) {
            float dot = 0.f;
            if (D % 4 == 0) {
                const float* xr = xj + jj * D;
                #pragma unroll
                for (int c4 = 0; c4 < D / 4; ++c4) {   // b128 broadcast reads
                    float4 v = *(const float4*)(xr + 4 * c4);
                    dot = fmaf(xi[4 * c4 + 0], v.x, dot);
                    dot = fmaf(xi[4 * c4 + 1], v.y, dot);
                    dot = fmaf(xi[4 * c4 + 2], v.z, dot);
                    dot = fmaf(xi[4 * c4 + 3], v.w, dot);
                }
            } else {
                #pragma unroll
                for (int c = 0; c < D; ++c) dot = fmaf(xi[c], xj[jj * D + c], dot);
            }
            float d = __builtin_fmaf(-2.f, dot, xxi + xxj[jj]);
            if (d < dl[20]) {                  // strict: ties keep earlier j
                dl[20] = d; il[20] = j0 + jj;
                #pragma unroll
                for (int t = 20; t > 0; --t) {
                    if (dl[t] < dl[t - 1]) {
                        float td = dl[t]; dl[t] = dl[t - 1]; dl[t - 1] = td;
                        int   ti = il[t]; il[t] = il[t - 1]; il[t - 1] = ti;
                    }
                }
            }
        }
    }
    unsigned short* cp =
        (unsigned short*)(xcat + (size_t)gi * 224 + 96) + s * 21;
    #pragma unroll
    for (int t = 0; t < 21; ++t) cp[t] = (unsigned short)il[t];
}

// ===================== KNN phase B: merge S x 21 candidates ================
template <int D, int RS, int S>
__global__ __launch_bounds__(256, 2) void knn_merge(
    const float* feat, const float* xcat, unsigned short* __restrict__ idxout) {
    int gi = blockIdx.x * 256 + threadIdx.x;
    int b  = gi >> 13;
    int ib = gi & (NPTS - 1);
    const float* fb = feat + (size_t)b * NPTS * RS;

    float xi[D];
    if (D % 4 == 0) {
        #pragma unroll
        for (int c4 = 0; c4 < D / 4; ++c4) {
            float4 v = *(const float4*)(fb + (size_t)ib * RS + 4 * c4);
            xi[4 * c4] = v.x; xi[4 * c4 + 1] = v.y;
            xi[4 * c4 + 2] = v.z; xi[4 * c4 + 3] = v.w;
        }
    } else {
        #pragma unroll
        for (int c = 0; c < D; ++c) xi[c] = fb[(size_t)ib * RS + c];
    }
    float xxi = 0.f;
    #pragma unroll
    for (int c = 0; c < D; ++c) xxi = fmaf(xi[c], xi[c], xxi);

    const unsigned short* cp =
        (const unsigned short*)(xcat + (size_t)gi * 224 + 96);

    float dl[21];
    int   il[21];
    #pragma unroll
    for (int t = 0; t < 21; ++t) { dl[t] = __builtin_inff(); il[t] = 0; }

    for (int t = 0; t < S * 21; ++t) {
        int j = ((int)cp[t]) & (NPTS - 1);
        const float* row = fb + (size_t)j * RS;
        float dot = 0.f, xx = 0.f;
        if (D % 4 == 0) {
            #pragma unroll
            for (int c4 = 0; c4 < D / 4; ++c4) {
                float4 v = *(const float4*)(row + 4 * c4);
                dot = fmaf(xi[4 * c4], v.x, dot);     xx = fmaf(v.x, v.x, xx);
                dot = fmaf(xi[4 * c4 + 1], v.y, dot); xx = fmaf(v.y, v.y, xx);
                dot = fmaf(xi[4 * c4 + 2], v.z, dot); xx = fmaf(v.z, v.z, xx);
                dot = fmaf(xi[4 * c4 + 3], v.w, dot); xx = fmaf(v.w, v.w, xx);
            }
        } else {
            #pragma unroll
            for (int c = 0; c < D; ++c) {
                float v = row[c];
                dot = fmaf(xi[c], v, dot);
                xx  = fmaf(v, v, xx);
            }
        }
        float d = __builtin_fmaf(-2.f, dot, xxi + xx);
        if (d < dl[20]) {
            dl[20] = d; il[20] = j;
            #pragma unroll
            for (int u = 20; u > 0; --u) {
                if (dl[u] < dl[u - 1]) {
                    float td = dl[u]; dl[u] = dl[u - 1]; dl[u - 1] = td;
                    int   ti = il[u]; il[u] = il[u - 1]; il[u - 1] = ti;
                }
            }
        }
    }
    unsigned short* op = idxout + (size_t)gi * KNBR;
    #pragma unroll
    for (int t = 1; t < 21; ++t) op[t - 1] = (unsigned short)il[t];
}

// ===================== EdgeConv (fused BN + leaky + max_k) =================
template <int CIN, int RS, int COUT, int OTILE, int P>
__global__ __launch_bounds__(256) void edgeconv_kernel(
    const float* feat, const unsigned short* __restrict__ knn,
    const float* __restrict__ W, const float* __restrict__ g,
    const float* __restrict__ beta, const float* __restrict__ mu,
    const float* __restrict__ var,
    float* outb, int concat_off) {
    __shared__ float diff[P][KNBR][CIN];
    __shared__ float xil[P][CIN];
    __shared__ unsigned short kidx[P * KNBR];
    __shared__ float sl[OTILE], bl[OTILE], ml[OTILE];

    int tid = threadIdx.x;
    int h   = blockIdx.y;
    int n0  = blockIdx.x * P;                 // P divides 8192 -> same batch
    int b   = n0 >> 13;
    const float* fbase = feat + ((size_t)b << 13) * RS;

    for (int e = tid; e < P * CIN; e += 256)
        xil[e / CIN][e % CIN] = feat[(size_t)(n0 + e / CIN) * RS + e % CIN];
    for (int e = tid; e < P * KNBR; e += 256)
        kidx[e] = knn[(size_t)(n0 + e / KNBR) * KNBR + e % KNBR] & (NPTS - 1);
    for (int e = tid; e < OTILE; e += 256) {
        int o = h * OTILE + e;
        sl[e] = g[o] * rsqrtf(var[o] + 1e-5f);
        bl[e] = beta[o];
        ml[e] = mu[o];
    }
    __syncthreads();

    if (CIN % 4 == 0) {
        for (int e = tid; e < P * KNBR * (CIN / 4); e += 256) {
            int r = e / (CIN / 4), c4 = e % (CIN / 4);
            int p = r / KNBR, k = r % KNBR;
            int j = (int)kidx[r];
            float4 v = *(const float4*)(fbase + (size_t)j * RS + 4 * c4);
            diff[p][k][4 * c4 + 0] = v.x - xil[p][4 * c4 + 0];
            diff[p][k][4 * c4 + 1] = v.y - xil[p][4 * c4 + 1];
            diff[p][k][4 * c4 + 2] = v.z - xil[p][4 * c4 + 2];
            diff[p][k][4 * c4 + 3] = v.w - xil[p][4 * c4 + 3];
        }
    } else {
        for (int e = tid; e < P * KNBR * CIN; e += 256) {
            int r = e / CIN, c = e % CIN;
            int pp = r / KNBR, k = r % KNBR;
            int j = (int)kidx[r];
            diff[pp][k][c] = fbase[(size_t)j * RS + c] - xil[pp][c];
        }
    }
    __syncthreads();

    int ol = tid % OTILE, p = tid / OTILE;
    int o  = h * OTILE + ol;

    float wreg[CIN];
    #pragma unroll
    for (int c = 0; c < CIN; ++c) wreg[c] = W[(size_t)o * (2 * CIN) + c];
    float a = 0.f;
    #pragma unroll
    for (int c = 0; c < CIN; ++c) a = fmaf(wreg[c], xil[p][c], a);
    #pragma unroll
    for (int c = 0; c < CIN; ++c) wreg[c] = W[(size_t)o * (2 * CIN) + CIN + c];

    float s = sl[ol], mm = ml[ol], bb = bl[ol];
    float best = -__builtin_inff();
    for (int k = 0; k < KNBR; ++k) {
        float ac0 = a, ac1 = 0.f, ac2 = 0.f, ac3 = 0.f;
        #pragma unroll
        for (int c = 0; c < CIN; ++c) {
            float d = diff[p][k][c];
            if ((c & 3) == 0)      ac0 = fmaf(wreg[c], d, ac0);
            else if ((c & 3) == 1) ac1 = fmaf(wreg[c], d, ac1);
            else if ((c & 3) == 2) ac2 = fmaf(wreg[c], d, ac2);
            else                   ac3 = fmaf(wreg[c], d, ac3);
        }
        float acc = ((ac0 + ac1) + ac2) + ac3;
        float y = (acc - mm) * s + bb;
        y = (y >= 0.f) ? y : 0.2f * y;
        best = fmaxf(best, y);
    }
    outb[(size_t)(n0 + p) * 224 + concat_off + o] = best;
}

// ===================== conv_global: LDS-tiled GEMM + fused max =============
__global__ __launch_bounds__(256) void convglobal_kernel(
    const float* __restrict__ xcat,
    const float* __restrict__ Wg, const float* __restrict__ gg,
    const float* __restrict__ bg, const float* __restrict__ mg,
    const float* __restrict__ vg,
    float* __restrict__ partial) {
    const int KC = 56, PT = 64, OT = 64, ST = 68;   // ST: padded row stride
    __shared__ float flT[KC * ST];                  // [c][p]  15.2 KB
    __shared__ float WlT[KC * ST];                  // [c][o]  15.2 KB
    __shared__ float red[64 * 17];                  //          4.4 KB

    int tid = threadIdx.x;
    int oi  = tid & 15, pi = tid >> 4;
    int o0  = blockIdx.y * OT;
    int n0  = blockIdx.x * PT;                      // 64 | 8192 -> same batch
    int b   = n0 >> 13;
    int pchunk = blockIdx.x & 127;                  // chunk within batch

    float acc[4][4];
    #pragma unroll
    for (int u = 0; u < 4; ++u)
        #pragma unroll
        for (int v = 0; v < 4; ++v) acc[u][v] = 0.f;

    for (int kc = 0; kc < 224; kc += KC) {
        __syncthreads();
        for (int e = tid; e < PT * (KC / 4); e += 256) {
            int p = e / (KC / 4), c4 = e % (KC / 4);
            float4 v = *(const float4*)(xcat + (size_t)(n0 + p) * 224 + kc + 4 * c4);
            flT[(4 * c4 + 0) * ST + p] = v.x;
            flT[(4 * c4 + 1) * ST + p] = v.y;
            flT[(4 * c4 + 2) * ST + p] = v.z;
            flT[(4 * c4 + 3) * ST + p] = v.w;
        }
        for (int e = tid; e < OT * (KC / 4); e += 256) {
            int o = e / (KC / 4), c4 = e % (KC / 4);
            float4 v = *(const float4*)(Wg + (size_t)(o0 + o) * 224 + kc + 4 * c4);
            WlT[(4 * c4 + 0) * ST + o] = v.x;
            WlT[(4 * c4 + 1) * ST + o] = v.y;
            WlT[(4 * c4 + 2) * ST + o] = v.z;
            WlT[(4 * c4 + 3) * ST + o] = v.w;
        }
        __syncthreads();
        #pragma unroll 8
        for (int c = 0; c < KC; ++c) {
            float4 w4 = *(const float4*)(WlT + c * ST + oi * 4);
            float4 f4 = *(const float4*)(flT + c * ST + pi * 4);
            acc[0][0] = fmaf(w4.x, f4.x, acc[0][0]);
            acc[0][1] = fmaf(w4.x, f4.y, acc[0][1]);
            acc[0][2] = fmaf(w4.x, f4.z, acc[0][2]);
            acc[0][3] = fmaf(w4.x, f4.w, acc[0][3]);
            acc[1][0] = fmaf(w4.y, f4.x, acc[1][0]);
            acc[1][1] = fmaf(w4.y, f4.y, acc[1][1]);
            acc[1][2] = fmaf(w4.y, f4.z, acc[1][2]);
            acc[1][3] = fmaf(w4.y, f4.w, acc[1][3]);
            acc[2][0] = fmaf(w4.z, f4.x, acc[2][0]);
            acc[2][1] = fmaf(w4.z, f4.y, acc[2][1]);
            acc[2][2] = fmaf(w4.z, f4.z, acc[2][2]);
            acc[2][3] = fmaf(w4.z, f4.w, acc[2][3]);
            acc[3][0] = fmaf(w4.w, f4.x, acc[3][0]);
            acc[3][1] = fmaf(w4.w, f4.y, acc[3][1]);
            acc[3][2] = fmaf(w4.w, f4.z, acc[3][2]);
            acc[3][3] = fmaf(w4.w, f4.w, acc[3][3]);
        }
    }
    #pragma unroll
    for (int u = 0; u < 4; ++u) {
        int oL = oi * 4 + u, o = o0 + oL;
        float s = gg[o] * rsqrtf(vg[o] + 1e-5f);
        float mm = mg[o], bb = bg[o];
        float best = -__builtin_inff();
        #pragma unroll
        for (int v = 0; v < 4; ++v) {
            float y = (acc[u][v] - mm) * s + bb;
            y = (y >= 0.f) ? y : 0.2f * y;
            best = fmaxf(best, y);
        }
        red[oL * 17 + pi] = best;
    }
    __syncthreads();
    if (tid < 64) {
        float best = -__builtin_inff();
        #pragma unroll
        for (int q = 0; q < 16; ++q) best = fmaxf(best, red[tid * 17 + q]);
        partial[((size_t)(b * 128 + pchunk)) * 256 + o0 + tid] = best;
    }
}

__global__ void reduce_gfeat_kernel(const float* __restrict__ partial,
                                    float* __restrict__ gfeat,
                                    float* __restrict__ outg) {
    int b = blockIdx.x, o = threadIdx.x;
    float best = -__builtin_inff();
    for (int ch = 0; ch < 128; ++ch)
        best = fmaxf(best, partial[((size_t)b * 128 + ch) * 256 + o]);
    gfeat[b * 256 + o] = best;
    outg[b * 256 + o]  = best;
}

// ===================== heads (per-batch block) =============================
__global__ __launch_bounds__(256) void heads_kernel(
    const float* __restrict__ gfeat,
    const float* __restrict__ Wv1, const float* __restrict__ bv1,
    const float* __restrict__ Wv2, const float* __restrict__ bv2,
    const float* __restrict__ Wq1, const float* __restrict__ bq1,
    const float* __restrict__ Wq2, const float* __restrict__ bq2,
    float* __restrict__ out) {
    int b = blockIdx.x, t = threadIdx.x;
    __shared__ float gf[256], h[512], q[64];
    gf[t] = gfeat[b * 256 + t];
    __syncthreads();
    for (int r = t; r < 512; r += 256) {
        float acc = bv1[r];
        for (int c = 0; c < 256; ++c) acc = fmaf(Wv1[r * 256 + c], gf[c], acc);
        h[r] = fmaxf(acc, 0.f);
    }
    __syncthreads();
    if (t < 192) {
        float acc = bv2[t];
        for (int c = 0; c < 512; ++c) acc = fmaf(Wv2[t * 512 + c], h[c], acc);
        out[b * 192 + t] = acc;               // vertex_coords
    } else {
        int r = t - 192;
        if (r < 64) {
            float acc = bq1[r];
            for (int c = 0; c < 256; ++c) acc = fmaf(Wq1[r * 256 + c], gf[c], acc);
            q[r] = fmaxf(acc, 0.f);
        }
    }
    __syncthreads();
    if (t == 0) {
        float acc = bq2[0];
        for (int c = 0; c < 64; ++c) acc = fmaf(Wq2[c], q[c], acc);
        float nv = 1.0f / (1.0f + expf(-acc));
        out[772 + b] = nv;                                       // nvs
        float num = fminf(fmaxf(rintf(nv * 64.0f), 1.0f), 64.0f);
        out[768 + b] = num;                                      // num_vertices
    }
}

// ============================== launch =====================================
extern "C" void kernel_launch(void* const* d_in, const int* in_sizes, int n_in,
                              void* d_out, int out_size, void* d_ws, size_t ws_size,
                              hipStream_t stream) {
    (void)in_sizes; (void)n_in; (void)out_size; (void)ws_size;
    const float* x   = (const float*)d_in[0];
    const float* W1  = (const float*)d_in[1];
    const float* g1  = (const float*)d_in[2];
    const float* b1  = (const float*)d_in[3];
    const float* m1  = (const float*)d_in[4];
    const float* v1  = (const float*)d_in[5];
    const float* W2  = (const float*)d_in[6];
    const float* g2  = (const float*)d_in[7];
    const float* b2  = (const float*)d_in[8];
    const float* m2  = (const float*)d_in[9];
    const float* v2  = (const float*)d_in[10];
    const float* W3  = (const float*)d_in[11];
    const float* g3  = (const float*)d_in[12];
    const float* b3  = (const float*)d_in[13];
    const float* m3  = (const float*)d_in[14];
    const float* v3  = (const float*)d_in[15];
    const float* Wg  = (const float*)d_in[16];
    const float* gg  = (const float*)d_in[17];
    const float* bg  = (const float*)d_in[18];
    const float* mg  = (const float*)d_in[19];
    const float* vg  = (const float*)d_in[20];
    const float* Wv1 = (const float*)d_in[21];
    const float* bv1 = (const float*)d_in[22];
    const float* Wv2 = (const float*)d_in[23];
    const float* bv2 = (const float*)d_in[24];
    const float* Wq1 = (const float*)d_in[25];
    const float* bq1 = (const float*)d_in[26];
    const float* Wq2 = (const float*)d_in[27];
    const float* bq2 = (const float*)d_in[28];

    float* out  = (float*)d_out;
    float* xcat = out + 1800;                    // f32 [4,8192,224]
    char* ws = (char*)d_ws;
    const int ROWS = BATCH * NPTS;   // 32768

    // ws layout (1,310,720 B; part/gft alias idx AFTER it is dead):
    unsigned short* idx  = (unsigned short*)(ws);        // [32768,20] u16
    float*          part = (float*)(ws);                 // [512,256] f32 (alias)
    float*          gft  = (float*)(ws + 524288);        // [4,256]   f32 (alias)

    // ---- EdgeConv 1: 5 -> 32
    knn_part<5, 5, 8, 128><<<dim3(ROWS / 128, 8), 128, 0, stream>>>(x, xcat);
    knn_merge<5, 5, 8><<<ROWS / 256, 256, 0, stream>>>(x, xcat, idx);
    edgeconv_kernel<5, 5, 32, 32, 8>
        <<<dim3(ROWS / 8, 1), 256, 0, stream>>>(x, idx, W1, g1, b1, m1, v1, xcat, 0);

    // ---- EdgeConv 2: 32 -> 64 (features from xcat[:,0:32))
    knn_part<32, 224, 8, 128><<<dim3(ROWS / 128, 8), 128, 0, stream>>>(xcat, xcat);
    knn_merge<32, 224, 8><<<ROWS / 256, 256, 0, stream>>>(xcat, xcat, idx);
    edgeconv_kernel<32, 224, 64, 64, 4>
        <<<dim3(ROWS / 4, 1), 256, 0, stream>>>(xcat, idx, W2, g2, b2, m2, v2, xcat, 32);

    // ---- EdgeConv 3: 64 -> 128 (features from xcat[:,32:96))
    knn_part<64, 224, 8, 64><<<dim3(ROWS / 128, 8), 128, 0, stream>>>(xcat + 32, xcat);
    knn_merge<64, 224, 8><<<ROWS / 256, 256, 0, stream>>>(xcat + 32, xcat, idx);
    edgeconv_kernel<64, 224, 128, 64, 4>
        <<<dim3(ROWS / 4, 2), 256, 0, stream>>>(xcat + 32, idx, W3, g3, b3, m3, v3, xcat, 96);

    // ---- conv_global (224->256) + max over N  (idx dead; part aliases it)
    convglobal_kernel<<<dim3(ROWS / 64, 4), 256, 0, stream>>>(
        xcat, Wg, gg, bg, mg, vg, part);
    reduce_gfeat_kernel<<<BATCH, 256, 0, stream>>>(part, gft, out + 776);

    // ---- heads
    heads_kernel<<<BATCH, 256, 0, stream>>>(
        gft, Wv1, bv1, Wv2, bv2, Wq1, bq1, Wq2, bq2, out);
}

// Round 10
// 6159.829 us; speedup vs baseline: 1.5153x; 1.5153x over previous
//
#include <hip/hip_runtime.h>
#include <hip/hip_bf16.h>

// ---------------------------------------------------------------------------
// BasicDGCNN forward, MI355X (gfx950). Inputs f32, output f32.
// Output layout (f32, flat): [0,768) vertex | [768,772) num_vertices |
// [772,776) nvs | [776,1800) gfeat | [1800,..) x_concat [4,8192,224].
//
// Round-10: REVERT round-9's launch_bounds experiment (regressed 2x, knob is
// non-monotonic here). One change vs round-8: KNN split S=8 -> 12 (ragged
// 683-j splits), TJ shrunk so LDS <= ~12.7KB -> 12 blocks/CU can co-reside
// (round-8: occupancy 24%, VALUBusy 80% -> ~1.3-1.5x issue headroom left).
// Candidate scratch 12*21 u16 = 504B fits the free 512B channel region.
// ws need = 1,310,720 B (idx; part/gft alias idx after dead) — proven safe.
// ---------------------------------------------------------------------------

#define NPTS 8192
#define BATCH 4
#define KNBR 20

// ===================== KNN phase A: per-split top-21 =======================
// grid (ROWS/128, S); block 128 threads; thread = query point; j-range
// [s*JC, min((s+1)*JC, NPTS)) staged in TJ-row LDS tiles (ragged tail ok,
// bounds are block-uniform). dist = xxi+xxj-2dot, ascending-c fma chains
// (bitwise-matched by the merge kernel). Candidates (21 u16, dist-sorted,
// ties j-ascending) -> xcat row scratch at f32 channel offset 96.
template <int D, int RS, int S, int TJ>
__global__ __launch_bounds__(128) void knn_part(
    const float* feat, float* xcat) {
    __shared__ float xj[TJ * D];
    __shared__ float xxj[TJ];
    const int JC = (NPTS + S - 1) / S;

    int gi = blockIdx.x * 128 + threadIdx.x;
    int s  = blockIdx.y;
    int b  = gi >> 13;
    int ib = gi & (NPTS - 1);
    const float* fb = feat + (size_t)b * NPTS * RS;

    int jbeg = s * JC;
    int jend = jbeg + JC < NPTS ? jbeg + JC : NPTS;

    float xi[D];
    if (D % 4 == 0) {
        #pragma unroll
        for (int c4 = 0; c4 < D / 4; ++c4) {
            float4 v = *(const float4*)(fb + (size_t)ib * RS + 4 * c4);
            xi[4 * c4] = v.x; xi[4 * c4 + 1] = v.y;
            xi[4 * c4 + 2] = v.z; xi[4 * c4 + 3] = v.w;
        }
    } else {
        #pragma unroll
        for (int c = 0; c < D; ++c) xi[c] = fb[(size_t)ib * RS + c];
    }
    float xxi = 0.f;
    #pragma unroll
    for (int c = 0; c < D; ++c) xxi = fmaf(xi[c], xi[c], xxi);

    float dl[21];
    int   il[21];
    #pragma unroll
    for (int t = 0; t < 21; ++t) { dl[t] = __builtin_inff(); il[t] = 0; }

    for (int j0 = jbeg; j0 < jend; j0 += TJ) {
        int rows = (jend - j0) < TJ ? (jend - j0) : TJ;   // block-uniform
        __syncthreads();                       // protect prior-iter reads
        if (D % 4 == 0) {
            for (int e = threadIdx.x; e < rows * (D / 4); e += 128) {
                int r = e / (D / 4), c4 = e % (D / 4);
                float4 v = *(const float4*)(fb + (size_t)(j0 + r) * RS + 4 * c4);
                *(float4*)(xj + r * D + 4 * c4) = v;
            }
        } else {
            for (int e = threadIdx.x; e < rows * D; e += 128) {
                int r = e / D, c = e % D;
                xj[e] = fb[(size_t)(j0 + r) * RS + c];
            }
        }
        // norms from GLOBAL (ascending-c fma chain == knn_merge's recompute)
        if (threadIdx.x < rows) {
            const float* row = fb + (size_t)(j0 + threadIdx.x) * RS;
            float sm = 0.f;
            if (D % 4 == 0) {
                #pragma unroll
                for (int c4 = 0; c4 < D / 4; ++c4) {
                    float4 v = *(const float4*)(row + 4 * c4);
                    sm = fmaf(v.x, v.x, sm); sm = fmaf(v.y, v.y, sm);
                    sm = fmaf(v.z, v.z, sm); sm = fmaf(v.w, v.w, sm);
                }
            } else {
                #pragma unroll
                for (int c = 0; c < D; ++c) sm = fmaf(row[c], row[c], sm);
            }
            xxj[threadIdx.x] = sm;
        }
        __syncthreads();
        for (int jj = 0; jj < rows; ++jj) {
            float dot = 0.f;
            if (D % 4 == 0) {
                const float* xr = xj + jj * D;
                #pragma unroll
                for (int c4 = 0; c4 < D / 4; ++c4) {   // b128 broadcast reads
                    float4 v = *(const float4*)(xr + 4 * c4);
                    dot = fmaf(xi[4 * c4 + 0], v.x, dot);
                    dot = fmaf(xi[4 * c4 + 1], v.y, dot);
                    dot = fmaf(xi[4 * c4 + 2], v.z, dot);
                    dot = fmaf(xi[4 * c4 + 3], v.w, dot);
                }
            } else {
                #pragma unroll
                for (int c = 0; c < D; ++c) dot = fmaf(xi[c], xj[jj * D + c], dot);
            }
            float d = __builtin_fmaf(-2.f, dot, xxi + xxj[jj]);
            if (d < dl[20]) {                  // strict: ties keep earlier j
                dl[20] = d; il[20] = j0 + jj;
                #pragma unroll
                for (int t = 20; t > 0; --t) {
                    if (dl[t] < dl[t - 1]) {
                        float td = dl[t]; dl[t] = dl[t - 1]; dl[t - 1] = td;
                        int   ti = il[t]; il[t] = il[t - 1]; il[t - 1] = ti;
                    }
                }
            }
        }
    }
    unsigned short* cp =
        (unsigned short*)(xcat + (size_t)gi * 224 + 96) + s * 21;
    #pragma unroll
    for (int t = 0; t < 21; ++t) cp[t] = (unsigned short)il[t];
}

// ===================== KNN phase B: merge S x 21 candidates ================
// Recompute d with the SAME fma ordering as knn_part; insert candidates in
// (split asc, stored rank) order with strict < -> stability == jax top_k.
template <int D, int RS, int S>
__global__ __launch_bounds__(256) void knn_merge(
    const float* feat, const float* xcat, unsigned short* __restrict__ idxout) {
    int gi = blockIdx.x * 256 + threadIdx.x;
    int b  = gi >> 13;
    int ib = gi & (NPTS - 1);
    const float* fb = feat + (size_t)b * NPTS * RS;

    float xi[D];
    if (D % 4 == 0) {
        #pragma unroll
        for (int c4 = 0; c4 < D / 4; ++c4) {
            float4 v = *(const float4*)(fb + (size_t)ib * RS + 4 * c4);
            xi[4 * c4] = v.x; xi[4 * c4 + 1] = v.y;
            xi[4 * c4 + 2] = v.z; xi[4 * c4 + 3] = v.w;
        }
    } else {
        #pragma unroll
        for (int c = 0; c < D; ++c) xi[c] = fb[(size_t)ib * RS + c];
    }
    float xxi = 0.f;
    #pragma unroll
    for (int c = 0; c < D; ++c) xxi = fmaf(xi[c], xi[c], xxi);

    const unsigned short* cp =
        (const unsigned short*)(xcat + (size_t)gi * 224 + 96);

    float dl[21];
    int   il[21];
    #pragma unroll
    for (int t = 0; t < 21; ++t) { dl[t] = __builtin_inff(); il[t] = 0; }

    for (int t = 0; t < S * 21; ++t) {
        int j = ((int)cp[t]) & (NPTS - 1);
        const float* row = fb + (size_t)j * RS;
        float dot = 0.f, xx = 0.f;
        if (D % 4 == 0) {
            #pragma unroll
            for (int c4 = 0; c4 < D / 4; ++c4) {
                float4 v = *(const float4*)(row + 4 * c4);
                dot = fmaf(xi[4 * c4], v.x, dot);     xx = fmaf(v.x, v.x, xx);
                dot = fmaf(xi[4 * c4 + 1], v.y, dot); xx = fmaf(v.y, v.y, xx);
                dot = fmaf(xi[4 * c4 + 2], v.z, dot); xx = fmaf(v.z, v.z, xx);
                dot = fmaf(xi[4 * c4 + 3], v.w, dot); xx = fmaf(v.w, v.w, xx);
            }
        } else {
            #pragma unroll
            for (int c = 0; c < D; ++c) {
                float v = row[c];
                dot = fmaf(xi[c], v, dot);
                xx  = fmaf(v, v, xx);
            }
        }
        float d = __builtin_fmaf(-2.f, dot, xxi + xx);
        if (d < dl[20]) {
            dl[20] = d; il[20] = j;
            #pragma unroll
            for (int u = 20; u > 0; --u) {
                if (dl[u] < dl[u - 1]) {
                    float td = dl[u]; dl[u] = dl[u - 1]; dl[u - 1] = td;
                    int   ti = il[u]; il[u] = il[u - 1]; il[u - 1] = ti;
                }
            }
        }
    }
    unsigned short* op = idxout + (size_t)gi * KNBR;
    #pragma unroll
    for (int t = 1; t < 21; ++t) op[t - 1] = (unsigned short)il[t];
}

// ===================== EdgeConv (fused BN + leaky + max_k) =================
template <int CIN, int RS, int COUT, int OTILE, int P>
__global__ __launch_bounds__(256) void edgeconv_kernel(
    const float* feat, const unsigned short* __restrict__ knn,
    const float* __restrict__ W, const float* __restrict__ g,
    const float* __restrict__ beta, const float* __restrict__ mu,
    const float* __restrict__ var,
    float* outb, int concat_off) {
    __shared__ float diff[P][KNBR][CIN];
    __shared__ float xil[P][CIN];
    __shared__ unsigned short kidx[P * KNBR];
    __shared__ float sl[OTILE], bl[OTILE], ml[OTILE];

    int tid = threadIdx.x;
    int h   = blockIdx.y;
    int n0  = blockIdx.x * P;                 // P divides 8192 -> same batch
    int b   = n0 >> 13;
    const float* fbase = feat + ((size_t)b << 13) * RS;

    for (int e = tid; e < P * CIN; e += 256)
        xil[e / CIN][e % CIN] = feat[(size_t)(n0 + e / CIN) * RS + e % CIN];
    for (int e = tid; e < P * KNBR; e += 256)
        kidx[e] = knn[(size_t)(n0 + e / KNBR) * KNBR + e % KNBR] & (NPTS - 1);
    for (int e = tid; e < OTILE; e += 256) {
        int o = h * OTILE + e;
        sl[e] = g[o] * rsqrtf(var[o] + 1e-5f);
        bl[e] = beta[o];
        ml[e] = mu[o];
    }
    __syncthreads();

    if (CIN % 4 == 0) {
        for (int e = tid; e < P * KNBR * (CIN / 4); e += 256) {
            int r = e / (CIN / 4), c4 = e % (CIN / 4);
            int p = r / KNBR, k = r % KNBR;
            int j = (int)kidx[r];
            float4 v = *(const float4*)(fbase + (size_t)j * RS + 4 * c4);
            diff[p][k][4 * c4 + 0] = v.x - xil[p][4 * c4 + 0];
            diff[p][k][4 * c4 + 1] = v.y - xil[p][4 * c4 + 1];
            diff[p][k][4 * c4 + 2] = v.z - xil[p][4 * c4 + 2];
            diff[p][k][4 * c4 + 3] = v.w - xil[p][4 * c4 + 3];
        }
    } else {
        for (int e = tid; e < P * KNBR * CIN; e += 256) {
            int r = e / CIN, c = e % CIN;
            int pp = r / KNBR, k = r % KNBR;
            int j = (int)kidx[r];
            diff[pp][k][c] = fbase[(size_t)j * RS + c] - xil[pp][c];
        }
    }
    __syncthreads();

    int ol = tid % OTILE, p = tid / OTILE;
    int o  = h * OTILE + ol;

    float wreg[CIN];
    #pragma unroll
    for (int c = 0; c < CIN; ++c) wreg[c] = W[(size_t)o * (2 * CIN) + c];
    float a = 0.f;
    #pragma unroll
    for (int c = 0; c < CIN; ++c) a = fmaf(wreg[c], xil[p][c], a);
    #pragma unroll
    for (int c = 0; c < CIN; ++c) wreg[c] = W[(size_t)o * (2 * CIN) + CIN + c];

    float s = sl[ol], mm = ml[ol], bb = bl[ol];
    float best = -__builtin_inff();
    for (int k = 0; k < KNBR; ++k) {
        float ac0 = a, ac1 = 0.f, ac2 = 0.f, ac3 = 0.f;
        #pragma unroll
        for (int c = 0; c < CIN; ++c) {
            float d = diff[p][k][c];
            if ((c & 3) == 0)      ac0 = fmaf(wreg[c], d, ac0);
            else if ((c & 3) == 1) ac1 = fmaf(wreg[c], d, ac1);
            else if ((c & 3) == 2) ac2 = fmaf(wreg[c], d, ac2);
            else                   ac3 = fmaf(wreg[c], d, ac3);
        }
        float acc = ((ac0 + ac1) + ac2) + ac3;
        float y = (acc - mm) * s + bb;
        y = (y >= 0.f) ? y : 0.2f * y;
        best = fmaxf(best, y);
    }
    outb[(size_t)(n0 + p) * 224 + concat_off + o] = best;
}

// ===================== conv_global: LDS-tiled GEMM + fused max =============
__global__ __launch_bounds__(256) void convglobal_kernel(
    const float* __restrict__ xcat,
    const float* __restrict__ Wg, const float* __restrict__ gg,
    const float* __restrict__ bg, const float* __restrict__ mg,
    const float* __restrict__ vg,
    float* __restrict__ partial) {
    const int KC = 56, PT = 64, OT = 64, ST = 68;   // ST: padded row stride
    __shared__ float flT[KC * ST];                  // [c][p]  15.2 KB
    __shared__ float WlT[KC * ST];                  // [c][o]  15.2 KB
    __shared__ float red[64 * 17];                  //          4.4 KB

    int tid = threadIdx.x;
    int oi  = tid & 15, pi = tid >> 4;
    int o0  = blockIdx.y * OT;
    int n0  = blockIdx.x * PT;                      // 64 | 8192 -> same batch
    int b   = n0 >> 13;
    int pchunk = blockIdx.x & 127;                  // chunk within batch

    float acc[4][4];
    #pragma unroll
    for (int u = 0; u < 4; ++u)
        #pragma unroll
        for (int v = 0; v < 4; ++v) acc[u][v] = 0.f;

    for (int kc = 0; kc < 224; kc += KC) {
        __syncthreads();
        for (int e = tid; e < PT * (KC / 4); e += 256) {
            int p = e / (KC / 4), c4 = e % (KC / 4);
            float4 v = *(const float4*)(xcat + (size_t)(n0 + p) * 224 + kc + 4 * c4);
            flT[(4 * c4 + 0) * ST + p] = v.x;
            flT[(4 * c4 + 1) * ST + p] = v.y;
            flT[(4 * c4 + 2) * ST + p] = v.z;
            flT[(4 * c4 + 3) * ST + p] = v.w;
        }
        for (int e = tid; e < OT * (KC / 4); e += 256) {
            int o = e / (KC / 4), c4 = e % (KC / 4);
            float4 v = *(const float4*)(Wg + (size_t)(o0 + o) * 224 + kc + 4 * c4);
            WlT[(4 * c4 + 0) * ST + o] = v.x;
            WlT[(4 * c4 + 1) * ST + o] = v.y;
            WlT[(4 * c4 + 2) * ST + o] = v.z;
            WlT[(4 * c4 + 3) * ST + o] = v.w;
        }
        __syncthreads();
        #pragma unroll 8
        for (int c = 0; c < KC; ++c) {
            float4 w4 = *(const float4*)(WlT + c * ST + oi * 4);
            float4 f4 = *(const float4*)(flT + c * ST + pi * 4);
            acc[0][0] = fmaf(w4.x, f4.x, acc[0][0]);
            acc[0][1] = fmaf(w4.x, f4.y, acc[0][1]);
            acc[0][2] = fmaf(w4.x, f4.z, acc[0][2]);
            acc[0][3] = fmaf(w4.x, f4.w, acc[0][3]);
            acc[1][0] = fmaf(w4.y, f4.x, acc[1][0]);
            acc[1][1] = fmaf(w4.y, f4.y, acc[1][1]);
            acc[1][2] = fmaf(w4.y, f4.z, acc[1][2]);
            acc[1][3] = fmaf(w4.y, f4.w, acc[1][3]);
            acc[2][0] = fmaf(w4.z, f4.x, acc[2][0]);
            acc[2][1] = fmaf(w4.z, f4.y, acc[2][1]);
            acc[2][2] = fmaf(w4.z, f4.z, acc[2][2]);
            acc[2][3] = fmaf(w4.z, f4.w, acc[2][3]);
            acc[3][0] = fmaf(w4.w, f4.x, acc[3][0]);
            acc[3][1] = fmaf(w4.w, f4.y, acc[3][1]);
            acc[3][2] = fmaf(w4.w, f4.z, acc[3][2]);
            acc[3][3] = fmaf(w4.w, f4.w, acc[3][3]);
        }
    }
    #pragma unroll
    for (int u = 0; u < 4; ++u) {
        int oL = oi * 4 + u, o = o0 + oL;
        float s = gg[o] * rsqrtf(vg[o] + 1e-5f);
        float mm = mg[o], bb = bg[o];
        float best = -__builtin_inff();
        #pragma unroll
        for (int v = 0; v < 4; ++v) {
            float y = (acc[u][v] - mm) * s + bb;
            y = (y >= 0.f) ? y : 0.2f * y;
            best = fmaxf(best, y);
        }
        red[oL * 17 + pi] = best;
    }
    __syncthreads();
    if (tid < 64) {
        float best = -__builtin_inff();
        #pragma unroll
        for (int q = 0; q < 16; ++q) best = fmaxf(best, red[tid * 17 + q]);
        partial[((size_t)(b * 128 + pchunk)) * 256 + o0 + tid] = best;
    }
}

__global__ void reduce_gfeat_kernel(const float* __restrict__ partial,
                                    float* __restrict__ gfeat,
                                    float* __restrict__ outg) {
    int b = blockIdx.x, o = threadIdx.x;
    float best = -__builtin_inff();
    for (int ch = 0; ch < 128; ++ch)
        best = fmaxf(best, partial[((size_t)b * 128 + ch) * 256 + o]);
    gfeat[b * 256 + o] = best;
    outg[b * 256 + o]  = best;
}

// ===================== heads (per-batch block) =============================
__global__ __launch_bounds__(256) void heads_kernel(
    const float* __restrict__ gfeat,
    const float* __restrict__ Wv1, const float* __restrict__ bv1,
    const float* __restrict__ Wv2, const float* __restrict__ bv2,
    const float* __restrict__ Wq1, const float* __restrict__ bq1,
    const float* __restrict__ Wq2, const float* __restrict__ bq2,
    float* __restrict__ out) {
    int b = blockIdx.x, t = threadIdx.x;
    __shared__ float gf[256], h[512], q[64];
    gf[t] = gfeat[b * 256 + t];
    __syncthreads();
    for (int r = t; r < 512; r += 256) {
        float acc = bv1[r];
        for (int c = 0; c < 256; ++c) acc = fmaf(Wv1[r * 256 + c], gf[c], acc);
        h[r] = fmaxf(acc, 0.f);
    }
    __syncthreads();
    if (t < 192) {
        float acc = bv2[t];
        for (int c = 0; c < 512; ++c) acc = fmaf(Wv2[t * 512 + c], h[c], acc);
        out[b * 192 + t] = acc;               // vertex_coords
    } else {
        int r = t - 192;
        if (r < 64) {
            float acc = bq1[r];
            for (int c = 0; c < 256; ++c) acc = fmaf(Wq1[r * 256 + c], gf[c], acc);
            q[r] = fmaxf(acc, 0.f);
        }
    }
    __syncthreads();
    if (t == 0) {
        float acc = bq2[0];
        for (int c = 0; c < 64; ++c) acc = fmaf(Wq2[c], q[c], acc);
        float nv = 1.0f / (1.0f + expf(-acc));
        out[772 + b] = nv;                                       // nvs
        float num = fminf(fmaxf(rintf(nv * 64.0f), 1.0f), 64.0f);
        out[768 + b] = num;                                      // num_vertices
    }
}

// ============================== launch =====================================
extern "C" void kernel_launch(void* const* d_in, const int* in_sizes, int n_in,
                              void* d_out, int out_size, void* d_ws, size_t ws_size,
                              hipStream_t stream) {
    (void)in_sizes; (void)n_in; (void)out_size; (void)ws_size;
    const float* x   = (const float*)d_in[0];
    const float* W1  = (const float*)d_in[1];
    const float* g1  = (const float*)d_in[2];
    const float* b1  = (const float*)d_in[3];
    const float* m1  = (const float*)d_in[4];
    const float* v1  = (const float*)d_in[5];
    const float* W2  = (const float*)d_in[6];
    const float* g2  = (const float*)d_in[7];
    const float* b2  = (const float*)d_in[8];
    const float* m2  = (const float*)d_in[9];
    const float* v2  = (const float*)d_in[10];
    const float* W3  = (const float*)d_in[11];
    const float* g3  = (const float*)d_in[12];
    const float* b3  = (const float*)d_in[13];
    const float* m3  = (const float*)d_in[14];
    const float* v3  = (const float*)d_in[15];
    const float* Wg  = (const float*)d_in[16];
    const float* gg  = (const float*)d_in[17];
    const float* bg  = (const float*)d_in[18];
    const float* mg  = (const float*)d_in[19];
    const float* vg  = (const float*)d_in[20];
    const float* Wv1 = (const float*)d_in[21];
    const float* bv1 = (const float*)d_in[22];
    const float* Wv2 = (const float*)d_in[23];
    const float* bv2 = (const float*)d_in[24];
    const float* Wq1 = (const float*)d_in[25];
    const float* bq1 = (const float*)d_in[26];
    const float* Wq2 = (const float*)d_in[27];
    const float* bq2 = (const float*)d_in[28];

    float* out  = (float*)d_out;
    float* xcat = out + 1800;                    // f32 [4,8192,224]
    char* ws = (char*)d_ws;
    const int ROWS = BATCH * NPTS;   // 32768

    // ws layout (1,310,720 B; part/gft alias idx AFTER it is dead):
    unsigned short* idx  = (unsigned short*)(ws);        // [32768,20] u16
    float*          part = (float*)(ws);                 // [512,256] f32 (alias)
    float*          gft  = (float*)(ws + 524288);        // [4,256]   f32 (alias)

    const int S = 12;   // 12*21 u16 = 504B scratch/row, fits [96,224) = 512B

    // ---- EdgeConv 1: 5 -> 32
    knn_part<5, 5, S, 128><<<dim3(ROWS / 128, S), 128, 0, stream>>>(x, xcat);
    knn_merge<5, 5, S><<<ROWS / 256, 256, 0, stream>>>(x, xcat, idx);
    edgeconv_kernel<5, 5, 32, 32, 8>
        <<<dim3(ROWS / 8, 1), 256, 0, stream>>>(x, idx, W1, g1, b1, m1, v1, xcat, 0);

    // ---- EdgeConv 2: 32 -> 64 (features from xcat[:,0:32))
    knn_part<32, 224, S, 96><<<dim3(ROWS / 128, S), 128, 0, stream>>>(xcat, xcat);
    knn_merge<32, 224, S><<<ROWS / 256, 256, 0, stream>>>(xcat, xcat, idx);
    edgeconv_kernel<32, 224, 64, 64, 4>
        <<<dim3(ROWS / 4, 1), 256, 0, stream>>>(xcat, idx, W2, g2, b2, m2, v2, xcat, 32);

    // ---- EdgeConv 3: 64 -> 128 (features from xcat[:,32:96))
    knn_part<64, 224, S, 48><<<dim3(ROWS / 128, S), 128, 0, stream>>>(xcat + 32, xcat);
    knn_merge<64, 224, S><<<ROWS / 256, 256, 0, stream>>>(xcat + 32, xcat, idx);
    edgeconv_kernel<64, 224, 128, 64, 4>
        <<<dim3(ROWS / 4, 2), 256, 0, stream>>>(xcat + 32, idx, W3, g3, b3, m3, v3, xcat, 96);

    // ---- conv_global (224->256) + max over N  (idx dead; part aliases it)
    convglobal_kernel<<<dim3(ROWS / 64, 4), 256, 0, stream>>>(
        xcat, Wg, gg, bg, mg, vg, part);
    reduce_gfeat_kernel<<<BATCH, 256, 0, stream>>>(part, gft, out + 776);

    // ---- heads
    heads_kernel<<<BATCH, 256, 0, stream>>>(
        gft, Wv1, bv1, Wv2, bv2, Wq1, bq1, Wq2, bq2, out);
}

// Round 11
// 3832.795 us; speedup vs baseline: 2.4354x; 1.6071x over previous
//
#include <hip/hip_runtime.h>
#include <hip/hip_bf16.h>

// ---------------------------------------------------------------------------
// BasicDGCNN forward, MI355X (gfx950). Inputs f32, output f32.
// Output layout (f32, flat): [0,768) vertex | [768,772) num_vertices |
// [772,776) nvs | [776,1800) gfeat | [1800,..) x_concat [4,8192,224].
//
// Round-11: revert to round-8 shape (S=8, TJ={128,128,64} — best, 4.37 ms;
// S=12 regressed). New: knn_part uses DEFERRED BUFFERED SELECTION — per-thread
// stale threshold + 8-slot LDS candidate buffer, drained through the exact
// insertion chain when any lane fills (__any). Bit-exact vs direct insertion
// (stale thr >= current dl[20] -> superset filter; drain re-checks in
// j-ascending order). Cuts wave-level chain executions ~7x; knn_part was
// issue-bound (VALUBusy 80%) with the chain ~half its instructions.
// ws need = 1,310,720 B (idx; part/gft alias idx after dead) — proven safe.
// ---------------------------------------------------------------------------

#define NPTS 8192
#define BATCH 4
#define KNBR 20

// ===================== KNN phase A: per-split top-21 =======================
// grid (ROWS/128, S); block 128 thr; thread = query point; j-range
// [s*1024,(s+1)*1024) staged in TJ-row LDS tiles. dist = xxi+xxj-2dot,
// ascending-c fma chains (bitwise-matched by knn_merge). Top-21 sorted,
// ties keep earlier j (== jax top_k of -dist). Candidates -> xcat row
// scratch at f32 channel offset 96 (8*21 u16 = 336B < 512B free).
template <int D, int RS, int S, int TJ, int B>
__global__ __launch_bounds__(128) void knn_part(
    const float* feat, float* xcat) {
    __shared__ float xj[TJ * D];
    __shared__ float xxj[TJ];
    __shared__ uint2 buf[128 * B];         // per-thread candidate buffer
    const int JC = NPTS / S;

    int gi = blockIdx.x * 128 + threadIdx.x;
    int s  = blockIdx.y;
    int b  = gi >> 13;
    int ib = gi & (NPTS - 1);
    const float* fb = feat + (size_t)b * NPTS * RS;
    uint2* mybuf = buf + threadIdx.x * B;

    float xi[D];
    if (D % 4 == 0) {
        #pragma unroll
        for (int c4 = 0; c4 < D / 4; ++c4) {
            float4 v = *(const float4*)(fb + (size_t)ib * RS + 4 * c4);
            xi[4 * c4] = v.x; xi[4 * c4 + 1] = v.y;
            xi[4 * c4 + 2] = v.z; xi[4 * c4 + 3] = v.w;
        }
    } else {
        #pragma unroll
        for (int c = 0; c < D; ++c) xi[c] = fb[(size_t)ib * RS + c];
    }
    float xxi = 0.f;
    #pragma unroll
    for (int c = 0; c < D; ++c) xxi = fmaf(xi[c], xi[c], xxi);

    float dl[21];
    int   il[21];
    #pragma unroll
    for (int t = 0; t < 21; ++t) { dl[t] = __builtin_inff(); il[t] = 0; }

    float thr = __builtin_inff();          // stale copy of dl[20]
    int   cnt = 0;

    for (int j0 = s * JC; j0 < (s + 1) * JC; j0 += TJ) {
        __syncthreads();                   // protect prior-iter reads
        if (D % 4 == 0) {
            for (int e = threadIdx.x; e < TJ * (D / 4); e += 128) {
                int r = e / (D / 4), c4 = e % (D / 4);
                float4 v = *(const float4*)(fb + (size_t)(j0 + r) * RS + 4 * c4);
                *(float4*)(xj + r * D + 4 * c4) = v;
            }
        } else {
            for (int e = threadIdx.x; e < TJ * D; e += 128) {
                int r = e / D, c = e % D;
                xj[e] = fb[(size_t)(j0 + r) * RS + c];
            }
        }
        // norms from GLOBAL (ascending-c fma chain == knn_merge's recompute)
        if (threadIdx.x < TJ) {
            const float* row = fb + (size_t)(j0 + threadIdx.x) * RS;
            float sm = 0.f;
            if (D % 4 == 0) {
                #pragma unroll
                for (int c4 = 0; c4 < D / 4; ++c4) {
                    float4 v = *(const float4*)(row + 4 * c4);
                    sm = fmaf(v.x, v.x, sm); sm = fmaf(v.y, v.y, sm);
                    sm = fmaf(v.z, v.z, sm); sm = fmaf(v.w, v.w, sm);
                }
            } else {
                #pragma unroll
                for (int c = 0; c < D; ++c) sm = fmaf(row[c], row[c], sm);
            }
            xxj[threadIdx.x] = sm;
        }
        __syncthreads();
        for (int jj = 0; jj < TJ; ++jj) {
            float dot = 0.f;
            if (D % 4 == 0) {
                const float* xr = xj + jj * D;
                #pragma unroll
                for (int c4 = 0; c4 < D / 4; ++c4) {   // b128 broadcast reads
                    float4 v = *(const float4*)(xr + 4 * c4);
                    dot = fmaf(xi[4 * c4 + 0], v.x, dot);
                    dot = fmaf(xi[4 * c4 + 1], v.y, dot);
                    dot = fmaf(xi[4 * c4 + 2], v.z, dot);
                    dot = fmaf(xi[4 * c4 + 3], v.w, dot);
                }
            } else {
                #pragma unroll
                for (int c = 0; c < D; ++c) dot = fmaf(xi[c], xj[jj * D + c], dot);
            }
            float d = __builtin_fmaf(-2.f, dot, xxi + xxj[jj]);
            if (__any(cnt == B)) {         // someone full -> all drain
                for (int u = 0; u < B; ++u) {
                    if (u < cnt) {
                        uint2 pk = mybuf[u];
                        float dd = __uint_as_float(pk.x);
                        if (dd < dl[20]) { // strict: ties keep earlier j
                            dl[20] = dd; il[20] = (int)pk.y;
                            #pragma unroll
                            for (int t = 20; t > 0; --t) {
                                if (dl[t] < dl[t - 1]) {
                                    float td = dl[t]; dl[t] = dl[t - 1]; dl[t - 1] = td;
                                    int   ti = il[t]; il[t] = il[t - 1]; il[t - 1] = ti;
                                }
                            }
                        }
                    }
                }
                cnt = 0;
                thr = dl[20];
            }
            if (d < thr) {                 // stale thr >= dl[20]: superset ok
                mybuf[cnt] = make_uint2(__float_as_uint(d), (unsigned)(j0 + jj));
                ++cnt;
            }
        }
    }
    // final drain
    for (int u = 0; u < B; ++u) {
        if (u < cnt) {
            uint2 pk = mybuf[u];
            float dd = __uint_as_float(pk.x);
            if (dd < dl[20]) {
                dl[20] = dd; il[20] = (int)pk.y;
                #pragma unroll
                for (int t = 20; t > 0; --t) {
                    if (dl[t] < dl[t - 1]) {
                        float td = dl[t]; dl[t] = dl[t - 1]; dl[t - 1] = td;
                        int   ti = il[t]; il[t] = il[t - 1]; il[t - 1] = ti;
                    }
                }
            }
        }
    }
    unsigned short* cp =
        (unsigned short*)(xcat + (size_t)gi * 224 + 96) + s * 21;
    #pragma unroll
    for (int t = 0; t < 21; ++t) cp[t] = (unsigned short)il[t];
}

// ===================== KNN phase B: merge S x 21 candidates ================
// Recompute d with the SAME fma ordering as knn_part; insert candidates in
// (split asc, stored rank) order with strict < -> stability == jax top_k.
// Drop entry 0 (self).
template <int D, int RS, int S>
__global__ __launch_bounds__(256) void knn_merge(
    const float* feat, const float* xcat, unsigned short* __restrict__ idxout) {
    int gi = blockIdx.x * 256 + threadIdx.x;
    int b  = gi >> 13;
    int ib = gi & (NPTS - 1);
    const float* fb = feat + (size_t)b * NPTS * RS;

    float xi[D];
    if (D % 4 == 0) {
        #pragma unroll
        for (int c4 = 0; c4 < D / 4; ++c4) {
            float4 v = *(const float4*)(fb + (size_t)ib * RS + 4 * c4);
            xi[4 * c4] = v.x; xi[4 * c4 + 1] = v.y;
            xi[4 * c4 + 2] = v.z; xi[4 * c4 + 3] = v.w;
        }
    } else {
        #pragma unroll
        for (int c = 0; c < D; ++c) xi[c] = fb[(size_t)ib * RS + c];
    }
    float xxi = 0.f;
    #pragma unroll
    for (int c = 0; c < D; ++c) xxi = fmaf(xi[c], xi[c], xxi);

    const unsigned short* cp =
        (const unsigned short*)(xcat + (size_t)gi * 224 + 96);

    float dl[21];
    int   il[21];
    #pragma unroll
    for (int t = 0; t < 21; ++t) { dl[t] = __builtin_inff(); il[t] = 0; }

    for (int t = 0; t < S * 21; ++t) {
        int j = ((int)cp[t]) & (NPTS - 1);
        const float* row = fb + (size_t)j * RS;
        float dot = 0.f, xx = 0.f;
        if (D % 4 == 0) {
            #pragma unroll
            for (int c4 = 0; c4 < D / 4; ++c4) {
                float4 v = *(const float4*)(row + 4 * c4);
                dot = fmaf(xi[4 * c4], v.x, dot);     xx = fmaf(v.x, v.x, xx);
                dot = fmaf(xi[4 * c4 + 1], v.y, dot); xx = fmaf(v.y, v.y, xx);
                dot = fmaf(xi[4 * c4 + 2], v.z, dot); xx = fmaf(v.z, v.z, xx);
                dot = fmaf(xi[4 * c4 + 3], v.w, dot); xx = fmaf(v.w, v.w, xx);
            }
        } else {
            #pragma unroll
            for (int c = 0; c < D; ++c) {
                float v = row[c];
                dot = fmaf(xi[c], v, dot);
                xx  = fmaf(v, v, xx);
            }
        }
        float d = __builtin_fmaf(-2.f, dot, xxi + xx);
        if (d < dl[20]) {
            dl[20] = d; il[20] = j;
            #pragma unroll
            for (int u = 20; u > 0; --u) {
                if (dl[u] < dl[u - 1]) {
                    float td = dl[u]; dl[u] = dl[u - 1]; dl[u - 1] = td;
                    int   ti = il[u]; il[u] = il[u - 1]; il[u - 1] = ti;
                }
            }
        }
    }
    unsigned short* op = idxout + (size_t)gi * KNBR;
    #pragma unroll
    for (int t = 1; t < 21; ++t) op[t - 1] = (unsigned short)il[t];
}

// ===================== EdgeConv (fused BN + leaky + max_k) =================
// Block: 256 thr = OTILE out-channels x P points; (x_j - x_i) staged f4-
// coalesced into LDS; W-row in registers; 4 accumulators. feat/outb may
// alias x_concat (disjoint channel ranges) -> no __restrict__ on them.
template <int CIN, int RS, int COUT, int OTILE, int P>
__global__ __launch_bounds__(256) void edgeconv_kernel(
    const float* feat, const unsigned short* __restrict__ knn,
    const float* __restrict__ W, const float* __restrict__ g,
    const float* __restrict__ beta, const float* __restrict__ mu,
    const float* __restrict__ var,
    float* outb, int concat_off) {
    __shared__ float diff[P][KNBR][CIN];
    __shared__ float xil[P][CIN];
    __shared__ unsigned short kidx[P * KNBR];
    __shared__ float sl[OTILE], bl[OTILE], ml[OTILE];

    int tid = threadIdx.x;
    int h   = blockIdx.y;
    int n0  = blockIdx.x * P;                 // P divides 8192 -> same batch
    int b   = n0 >> 13;
    const float* fbase = feat + ((size_t)b << 13) * RS;

    for (int e = tid; e < P * CIN; e += 256)
        xil[e / CIN][e % CIN] = feat[(size_t)(n0 + e / CIN) * RS + e % CIN];
    for (int e = tid; e < P * KNBR; e += 256)
        kidx[e] = knn[(size_t)(n0 + e / KNBR) * KNBR + e % KNBR] & (NPTS - 1);
    for (int e = tid; e < OTILE; e += 256) {
        int o = h * OTILE + e;
        sl[e] = g[o] * rsqrtf(var[o] + 1e-5f);
        bl[e] = beta[o];
        ml[e] = mu[o];
    }
    __syncthreads();

    if (CIN % 4 == 0) {
        for (int e = tid; e < P * KNBR * (CIN / 4); e += 256) {
            int r = e / (CIN / 4), c4 = e % (CIN / 4);
            int p = r / KNBR, k = r % KNBR;
            int j = (int)kidx[r];
            float4 v = *(const float4*)(fbase + (size_t)j * RS + 4 * c4);
            diff[p][k][4 * c4 + 0] = v.x - xil[p][4 * c4 + 0];
            diff[p][k][4 * c4 + 1] = v.y - xil[p][4 * c4 + 1];
            diff[p][k][4 * c4 + 2] = v.z - xil[p][4 * c4 + 2];
            diff[p][k][4 * c4 + 3] = v.w - xil[p][4 * c4 + 3];
        }
    } else {
        for (int e = tid; e < P * KNBR * CIN; e += 256) {
            int r = e / CIN, c = e % CIN;
            int pp = r / KNBR, k = r % KNBR;
            int j = (int)kidx[r];
            diff[pp][k][c] = fbase[(size_t)j * RS + c] - xil[pp][c];
        }
    }
    __syncthreads();

    int ol = tid % OTILE, p = tid / OTILE;
    int o  = h * OTILE + ol;

    float wreg[CIN];
    #pragma unroll
    for (int c = 0; c < CIN; ++c) wreg[c] = W[(size_t)o * (2 * CIN) + c];
    float a = 0.f;
    #pragma unroll
    for (int c = 0; c < CIN; ++c) a = fmaf(wreg[c], xil[p][c], a);
    #pragma unroll
    for (int c = 0; c < CIN; ++c) wreg[c] = W[(size_t)o * (2 * CIN) + CIN + c];

    float s = sl[ol], mm = ml[ol], bb = bl[ol];
    float best = -__builtin_inff();
    for (int k = 0; k < KNBR; ++k) {
        float ac0 = a, ac1 = 0.f, ac2 = 0.f, ac3 = 0.f;
        #pragma unroll
        for (int c = 0; c < CIN; ++c) {
            float d = diff[p][k][c];
            if ((c & 3) == 0)      ac0 = fmaf(wreg[c], d, ac0);
            else if ((c & 3) == 1) ac1 = fmaf(wreg[c], d, ac1);
            else if ((c & 3) == 2) ac2 = fmaf(wreg[c], d, ac2);
            else                   ac3 = fmaf(wreg[c], d, ac3);
        }
        float acc = ((ac0 + ac1) + ac2) + ac3;
        float y = (acc - mm) * s + bb;
        y = (y >= 0.f) ? y : 0.2f * y;
        best = fmaxf(best, y);
    }
    outb[(size_t)(n0 + p) * 224 + concat_off + o] = best;
}

// ===================== conv_global: LDS-tiled GEMM + fused max =============
__global__ __launch_bounds__(256) void convglobal_kernel(
    const float* __restrict__ xcat,
    const float* __restrict__ Wg, const float* __restrict__ gg,
    const float* __restrict__ bg, const float* __restrict__ mg,
    const float* __restrict__ vg,
    float* __restrict__ partial) {
    const int KC = 56, PT = 64, OT = 64, ST = 68;   // ST: padded row stride
    __shared__ float flT[KC * ST];                  // [c][p]  15.2 KB
    __shared__ float WlT[KC * ST];                  // [c][o]  15.2 KB
    __shared__ float red[64 * 17];                  //          4.4 KB

    int tid = threadIdx.x;
    int oi  = tid & 15, pi = tid >> 4;
    int o0  = blockIdx.y * OT;
    int n0  = blockIdx.x * PT;                      // 64 | 8192 -> same batch
    int b   = n0 >> 13;
    int pchunk = blockIdx.x & 127;                  // chunk within batch

    float acc[4][4];
    #pragma unroll
    for (int u = 0; u < 4; ++u)
        #pragma unroll
        for (int v = 0; v < 4; ++v) acc[u][v] = 0.f;

    for (int kc = 0; kc < 224; kc += KC) {
        __syncthreads();
        for (int e = tid; e < PT * (KC / 4); e += 256) {
            int p = e / (KC / 4), c4 = e % (KC / 4);
            float4 v = *(const float4*)(xcat + (size_t)(n0 + p) * 224 + kc + 4 * c4);
            flT[(4 * c4 + 0) * ST + p] = v.x;
            flT[(4 * c4 + 1) * ST + p] = v.y;
            flT[(4 * c4 + 2) * ST + p] = v.z;
            flT[(4 * c4 + 3) * ST + p] = v.w;
        }
        for (int e = tid; e < OT * (KC / 4); e += 256) {
            int o = e / (KC / 4), c4 = e % (KC / 4);
            float4 v = *(const float4*)(Wg + (size_t)(o0 + o) * 224 + kc + 4 * c4);
            WlT[(4 * c4 + 0) * ST + o] = v.x;
            WlT[(4 * c4 + 1) * ST + o] = v.y;
            WlT[(4 * c4 + 2) * ST + o] = v.z;
            WlT[(4 * c4 + 3) * ST + o] = v.w;
        }
        __syncthreads();
        #pragma unroll 8
        for (int c = 0; c < KC; ++c) {
            float4 w4 = *(const float4*)(WlT + c * ST + oi * 4);
            float4 f4 = *(const float4*)(flT + c * ST + pi * 4);
            acc[0][0] = fmaf(w4.x, f4.x, acc[0][0]);
            acc[0][1] = fmaf(w4.x, f4.y, acc[0][1]);
            acc[0][2] = fmaf(w4.x, f4.z, acc[0][2]);
            acc[0][3] = fmaf(w4.x, f4.w, acc[0][3]);
            acc[1][0] = fmaf(w4.y, f4.x, acc[1][0]);
            acc[1][1] = fmaf(w4.y, f4.y, acc[1][1]);
            acc[1][2] = fmaf(w4.y, f4.z, acc[1][2]);
            acc[1][3] = fmaf(w4.y, f4.w, acc[1][3]);
            acc[2][0] = fmaf(w4.z, f4.x, acc[2][0]);
            acc[2][1] = fmaf(w4.z, f4.y, acc[2][1]);
            acc[2][2] = fmaf(w4.z, f4.z, acc[2][2]);
            acc[2][3] = fmaf(w4.z, f4.w, acc[2][3]);
            acc[3][0] = fmaf(w4.w, f4.x, acc[3][0]);
            acc[3][1] = fmaf(w4.w, f4.y, acc[3][1]);
            acc[3][2] = fmaf(w4.w, f4.z, acc[3][2]);
            acc[3][3] = fmaf(w4.w, f4.w, acc[3][3]);
        }
    }
    #pragma unroll
    for (int u = 0; u < 4; ++u) {
        int oL = oi * 4 + u, o = o0 + oL;
        float s = gg[o] * rsqrtf(vg[o] + 1e-5f);
        float mm = mg[o], bb = bg[o];
        float best = -__builtin_inff();
        #pragma unroll
        for (int v = 0; v < 4; ++v) {
            float y = (acc[u][v] - mm) * s + bb;
            y = (y >= 0.f) ? y : 0.2f * y;
            best = fmaxf(best, y);
        }
        red[oL * 17 + pi] = best;
    }
    __syncthreads();
    if (tid < 64) {
        float best = -__builtin_inff();
        #pragma unroll
        for (int q = 0; q < 16; ++q) best = fmaxf(best, red[tid * 17 + q]);
        partial[((size_t)(b * 128 + pchunk)) * 256 + o0 + tid] = best;
    }
}

__global__ void reduce_gfeat_kernel(const float* __restrict__ partial,
                                    float* __restrict__ gfeat,
                                    float* __restrict__ outg) {
    int b = blockIdx.x, o = threadIdx.x;
    float best = -__builtin_inff();
    for (int ch = 0; ch < 128; ++ch)
        best = fmaxf(best, partial[((size_t)b * 128 + ch) * 256 + o]);
    gfeat[b * 256 + o] = best;
    outg[b * 256 + o]  = best;
}

// ===================== heads (per-batch block) =============================
__global__ __launch_bounds__(256) void heads_kernel(
    const float* __restrict__ gfeat,
    const float* __restrict__ Wv1, const float* __restrict__ bv1,
    const float* __restrict__ Wv2, const float* __restrict__ bv2,
    const float* __restrict__ Wq1, const float* __restrict__ bq1,
    const float* __restrict__ Wq2, const float* __restrict__ bq2,
    float* __restrict__ out) {
    int b = blockIdx.x, t = threadIdx.x;
    __shared__ float gf[256], h[512], q[64];
    gf[t] = gfeat[b * 256 + t];
    __syncthreads();
    for (int r = t; r < 512; r += 256) {
        float acc = bv1[r];
        for (int c = 0; c < 256; ++c) acc = fmaf(Wv1[r * 256 + c], gf[c], acc);
        h[r] = fmaxf(acc, 0.f);
    }
    __syncthreads();
    if (t < 192) {
        float acc = bv2[t];
        for (int c = 0; c < 512; ++c) acc = fmaf(Wv2[t * 512 + c], h[c], acc);
        out[b * 192 + t] = acc;               // vertex_coords
    } else {
        int r = t - 192;
        if (r < 64) {
            float acc = bq1[r];
            for (int c = 0; c < 256; ++c) acc = fmaf(Wq1[r * 256 + c], gf[c], acc);
            q[r] = fmaxf(acc, 0.f);
        }
    }
    __syncthreads();
    if (t == 0) {
        float acc = bq2[0];
        for (int c = 0; c < 64; ++c) acc = fmaf(Wq2[c], q[c], acc);
        float nv = 1.0f / (1.0f + expf(-acc));
        out[772 + b] = nv;                                       // nvs
        float num = fminf(fmaxf(rintf(nv * 64.0f), 1.0f), 64.0f);
        out[768 + b] = num;                                      // num_vertices
    }
}

// ============================== launch =====================================
extern "C" void kernel_launch(void* const* d_in, const int* in_sizes, int n_in,
                              void* d_out, int out_size, void* d_ws, size_t ws_size,
                              hipStream_t stream) {
    (void)in_sizes; (void)n_in; (void)out_size; (void)ws_size;
    const float* x   = (const float*)d_in[0];
    const float* W1  = (const float*)d_in[1];
    const float* g1  = (const float*)d_in[2];
    const float* b1  = (const float*)d_in[3];
    const float* m1  = (const float*)d_in[4];
    const float* v1  = (const float*)d_in[5];
    const float* W2  = (const float*)d_in[6];
    const float* g2  = (const float*)d_in[7];
    const float* b2  = (const float*)d_in[8];
    const float* m2  = (const float*)d_in[9];
    const float* v2  = (const float*)d_in[10];
    const float* W3  = (const float*)d_in[11];
    const float* g3  = (const float*)d_in[12];
    const float* b3  = (const float*)d_in[13];
    const float* m3  = (const float*)d_in[14];
    const float* v3  = (const float*)d_in[15];
    const float* Wg  = (const float*)d_in[16];
    const float* gg  = (const float*)d_in[17];
    const float* bg  = (const float*)d_in[18];
    const float* mg  = (const float*)d_in[19];
    const float* vg  = (const float*)d_in[20];
    const float* Wv1 = (const float*)d_in[21];
    const float* bv1 = (const float*)d_in[22];
    const float* Wv2 = (const float*)d_in[23];
    const float* bv2 = (const float*)d_in[24];
    const float* Wq1 = (const float*)d_in[25];
    const float* bq1 = (const float*)d_in[26];
    const float* Wq2 = (const float*)d_in[27];
    const float* bq2 = (const float*)d_in[28];

    float* out  = (float*)d_out;
    float* xcat = out + 1800;                    // f32 [4,8192,224]
    char* ws = (char*)d_ws;
    const int ROWS = BATCH * NPTS;   // 32768

    // ws layout (1,310,720 B; part/gft alias idx AFTER it is dead):
    unsigned short* idx  = (unsigned short*)(ws);        // [32768,20] u16
    float*          part = (float*)(ws);                 // [512,256] f32 (alias)
    float*          gft  = (float*)(ws + 524288);        // [4,256]   f32 (alias)

    // ---- EdgeConv 1: 5 -> 32
    knn_part<5, 5, 8, 128, 8><<<dim3(ROWS / 128, 8), 128, 0, stream>>>(x, xcat);
    knn_merge<5, 5, 8><<<ROWS / 256, 256, 0, stream>>>(x, xcat, idx);
    edgeconv_kernel<5, 5, 32, 32, 8>
        <<<dim3(ROWS / 8, 1), 256, 0, stream>>>(x, idx, W1, g1, b1, m1, v1, xcat, 0);

    // ---- EdgeConv 2: 32 -> 64 (features from xcat[:,0:32))
    knn_part<32, 224, 8, 128, 8><<<dim3(ROWS / 128, 8), 128, 0, stream>>>(xcat, xcat);
    knn_merge<32, 224, 8><<<ROWS / 256, 256, 0, stream>>>(xcat, xcat, idx);
    edgeconv_kernel<32, 224, 64, 64, 4>
        <<<dim3(ROWS / 4, 1), 256, 0, stream>>>(xcat, idx, W2, g2, b2, m2, v2, xcat, 32);

    // ---- EdgeConv 3: 64 -> 128 (features from xcat[:,32:96))
    knn_part<64, 224, 8, 64, 8><<<dim3(ROWS / 128, 8), 128, 0, stream>>>(xcat + 32, xcat);
    knn_merge<64, 224, 8><<<ROWS / 256, 256, 0, stream>>>(xcat + 32, xcat, idx);
    edgeconv_kernel<64, 224, 128, 64, 4>
        <<<dim3(ROWS / 4, 2), 256, 0, stream>>>(xcat + 32, idx, W3, g3, b3, m3, v3, xcat, 96);

    // ---- conv_global (224->256) + max over N  (idx dead; part aliases it)
    convglobal_kernel<<<dim3(ROWS / 64, 4), 256, 0, stream>>>(
        xcat, Wg, gg, bg, mg, vg, part);
    reduce_gfeat_kernel<<<BATCH, 256, 0, stream>>>(part, gft, out + 776);

    // ---- heads
    heads_kernel<<<BATCH, 256, 0, stream>>>(
        gft, Wv1, bv1, Wv2, bv2, Wq1, bq1, Wq2, bq2, out);
}

// Round 12
// 3790.326 us; speedup vs baseline: 2.4627x; 1.0112x over previous
//
#include <hip/hip_runtime.h>
#include <hip/hip_bf16.h>

// ---------------------------------------------------------------------------
// BasicDGCNN forward, MI355X (gfx950). Inputs f32, output f32.
// Output layout (f32, flat): [0,768) vertex | [768,772) num_vertices |
// [772,776) nvs | [776,1800) gfeat | [1800,..) x_concat [4,8192,224].
//
// Round-12: fix round-11's buffer bank conflicts (3.3e7 SQ_LDS_BANK_CONFLICT:
// uint2 buf[tid][u] gave lane-stride 16 words -> 32-way conflicts on append
// AND drain). New layout: bufd[u][128] f32 (lane-stride 1 -> conflict-free) +
// bufj[u][128] u16 (2 lanes/bank -> free). Logic bit-identical; LDS 25->22.6KB.
// ws need = 1,310,720 B (idx; part/gft alias idx after dead) — proven safe.
// ---------------------------------------------------------------------------

#define NPTS 8192
#define BATCH 4
#define KNBR 20

// ===================== KNN phase A: per-split top-21 =======================
// grid (ROWS/128, S); block 128 thr; thread = query point; j-range
// [s*1024,(s+1)*1024) staged in TJ-row LDS tiles. dist = xxi+xxj-2dot,
// ascending-c fma chains (bitwise-matched by knn_merge). Deferred buffered
// selection: stale per-thread threshold + B-slot LDS buffer, drained through
// the exact insertion chain when any lane fills (__any) — bit-exact vs
// direct insertion (superset filter; drain re-checks in j-ascending order).
// Top-21 sorted, ties keep earlier j. Candidates -> xcat row scratch @96.
template <int D, int RS, int S, int TJ, int B>
__global__ __launch_bounds__(128) void knn_part(
    const float* feat, float* xcat) {
    __shared__ float xj[TJ * D];
    __shared__ float xxj[TJ];
    __shared__ float bufd[B * 128];            // [slot][lane]: stride-1, no conflicts
    __shared__ unsigned short bufj[B * 128];   // u16: 2 lanes/bank = free
    const int JC = NPTS / S;

    int gi = blockIdx.x * 128 + threadIdx.x;
    int s  = blockIdx.y;
    int b  = gi >> 13;
    int ib = gi & (NPTS - 1);
    const float* fb = feat + (size_t)b * NPTS * RS;
    int tid = threadIdx.x;

    float xi[D];
    if (D % 4 == 0) {
        #pragma unroll
        for (int c4 = 0; c4 < D / 4; ++c4) {
            float4 v = *(const float4*)(fb + (size_t)ib * RS + 4 * c4);
            xi[4 * c4] = v.x; xi[4 * c4 + 1] = v.y;
            xi[4 * c4 + 2] = v.z; xi[4 * c4 + 3] = v.w;
        }
    } else {
        #pragma unroll
        for (int c = 0; c < D; ++c) xi[c] = fb[(size_t)ib * RS + c];
    }
    float xxi = 0.f;
    #pragma unroll
    for (int c = 0; c < D; ++c) xxi = fmaf(xi[c], xi[c], xxi);

    float dl[21];
    int   il[21];
    #pragma unroll
    for (int t = 0; t < 21; ++t) { dl[t] = __builtin_inff(); il[t] = 0; }

    float thr = __builtin_inff();          // stale copy of dl[20]
    int   cnt = 0;

    for (int j0 = s * JC; j0 < (s + 1) * JC; j0 += TJ) {
        __syncthreads();                   // protect prior-iter reads
        if (D % 4 == 0) {
            for (int e = tid; e < TJ * (D / 4); e += 128) {
                int r = e / (D / 4), c4 = e % (D / 4);
                float4 v = *(const float4*)(fb + (size_t)(j0 + r) * RS + 4 * c4);
                *(float4*)(xj + r * D + 4 * c4) = v;
            }
        } else {
            for (int e = tid; e < TJ * D; e += 128) {
                int r = e / D, c = e % D;
                xj[e] = fb[(size_t)(j0 + r) * RS + c];
            }
        }
        // norms from GLOBAL (ascending-c fma chain == knn_merge's recompute)
        if (tid < TJ) {
            const float* row = fb + (size_t)(j0 + tid) * RS;
            float sm = 0.f;
            if (D % 4 == 0) {
                #pragma unroll
                for (int c4 = 0; c4 < D / 4; ++c4) {
                    float4 v = *(const float4*)(row + 4 * c4);
                    sm = fmaf(v.x, v.x, sm); sm = fmaf(v.y, v.y, sm);
                    sm = fmaf(v.z, v.z, sm); sm = fmaf(v.w, v.w, sm);
                }
            } else {
                #pragma unroll
                for (int c = 0; c < D; ++c) sm = fmaf(row[c], row[c], sm);
            }
            xxj[tid] = sm;
        }
        __syncthreads();
        for (int jj = 0; jj < TJ; ++jj) {
            float dot = 0.f;
            if (D % 4 == 0) {
                const float* xr = xj + jj * D;
                #pragma unroll
                for (int c4 = 0; c4 < D / 4; ++c4) {   // b128 broadcast reads
                    float4 v = *(const float4*)(xr + 4 * c4);
                    dot = fmaf(xi[4 * c4 + 0], v.x, dot);
                    dot = fmaf(xi[4 * c4 + 1], v.y, dot);
                    dot = fmaf(xi[4 * c4 + 2], v.z, dot);
                    dot = fmaf(xi[4 * c4 + 3], v.w, dot);
                }
            } else {
                #pragma unroll
                for (int c = 0; c < D; ++c) dot = fmaf(xi[c], xj[jj * D + c], dot);
            }
            float d = __builtin_fmaf(-2.f, dot, xxi + xxj[jj]);
            if (__any(cnt == B)) {         // someone full -> all drain
                for (int u = 0; u < B; ++u) {
                    if (u < cnt) {
                        float dd = bufd[u * 128 + tid];
                        int   jj2 = (int)bufj[u * 128 + tid];
                        if (dd < dl[20]) { // strict: ties keep earlier j
                            dl[20] = dd; il[20] = jj2;
                            #pragma unroll
                            for (int t = 20; t > 0; --t) {
                                if (dl[t] < dl[t - 1]) {
                                    float td = dl[t]; dl[t] = dl[t - 1]; dl[t - 1] = td;
                                    int   ti = il[t]; il[t] = il[t - 1]; il[t - 1] = ti;
                                }
                            }
                        }
                    }
                }
                cnt = 0;
                thr = dl[20];
            }
            if (d < thr) {                 // stale thr >= dl[20]: superset ok
                bufd[cnt * 128 + tid] = d;
                bufj[cnt * 128 + tid] = (unsigned short)(j0 + jj);
                ++cnt;
            }
        }
    }
    // final drain
    for (int u = 0; u < B; ++u) {
        if (u < cnt) {
            float dd = bufd[u * 128 + tid];
            int   jj2 = (int)bufj[u * 128 + tid];
            if (dd < dl[20]) {
                dl[20] = dd; il[20] = jj2;
                #pragma unroll
                for (int t = 20; t > 0; --t) {
                    if (dl[t] < dl[t - 1]) {
                        float td = dl[t]; dl[t] = dl[t - 1]; dl[t - 1] = td;
                        int   ti = il[t]; il[t] = il[t - 1]; il[t - 1] = ti;
                    }
                }
            }
        }
    }
    unsigned short* cp =
        (unsigned short*)(xcat + (size_t)gi * 224 + 96) + s * 21;
    #pragma unroll
    for (int t = 0; t < 21; ++t) cp[t] = (unsigned short)il[t];
}

// ===================== KNN phase B: merge S x 21 candidates ================
// Recompute d with the SAME fma ordering as knn_part; insert candidates in
// (split asc, stored rank) order with strict < -> stability == jax top_k.
// Drop entry 0 (self).
template <int D, int RS, int S>
__global__ __launch_bounds__(256) void knn_merge(
    const float* feat, const float* xcat, unsigned short* __restrict__ idxout) {
    int gi = blockIdx.x * 256 + threadIdx.x;
    int b  = gi >> 13;
    int ib = gi & (NPTS - 1);
    const float* fb = feat + (size_t)b * NPTS * RS;

    float xi[D];
    if (D % 4 == 0) {
        #pragma unroll
        for (int c4 = 0; c4 < D / 4; ++c4) {
            float4 v = *(const float4*)(fb + (size_t)ib * RS + 4 * c4);
            xi[4 * c4] = v.x; xi[4 * c4 + 1] = v.y;
            xi[4 * c4 + 2] = v.z; xi[4 * c4 + 3] = v.w;
        }
    } else {
        #pragma unroll
        for (int c = 0; c < D; ++c) xi[c] = fb[(size_t)ib * RS + c];
    }
    float xxi = 0.f;
    #pragma unroll
    for (int c = 0; c < D; ++c) xxi = fmaf(xi[c], xi[c], xxi);

    const unsigned short* cp =
        (const unsigned short*)(xcat + (size_t)gi * 224 + 96);

    float dl[21];
    int   il[21];
    #pragma unroll
    for (int t = 0; t < 21; ++t) { dl[t] = __builtin_inff(); il[t] = 0; }

    for (int t = 0; t < S * 21; ++t) {
        int j = ((int)cp[t]) & (NPTS - 1);
        const float* row = fb + (size_t)j * RS;
        float dot = 0.f, xx = 0.f;
        if (D % 4 == 0) {
            #pragma unroll
            for (int c4 = 0; c4 < D / 4; ++c4) {
                float4 v = *(const float4*)(row + 4 * c4);
                dot = fmaf(xi[4 * c4], v.x, dot);     xx = fmaf(v.x, v.x, xx);
                dot = fmaf(xi[4 * c4 + 1], v.y, dot); xx = fmaf(v.y, v.y, xx);
                dot = fmaf(xi[4 * c4 + 2], v.z, dot); xx = fmaf(v.z, v.z, xx);
                dot = fmaf(xi[4 * c4 + 3], v.w, dot); xx = fmaf(v.w, v.w, xx);
            }
        } else {
            #pragma unroll
            for (int c = 0; c < D; ++c) {
                float v = row[c];
                dot = fmaf(xi[c], v, dot);
                xx  = fmaf(v, v, xx);
            }
        }
        float d = __builtin_fmaf(-2.f, dot, xxi + xx);
        if (d < dl[20]) {
            dl[20] = d; il[20] = j;
            #pragma unroll
            for (int u = 20; u > 0; --u) {
                if (dl[u] < dl[u - 1]) {
                    float td = dl[u]; dl[u] = dl[u - 1]; dl[u - 1] = td;
                    int   ti = il[u]; il[u] = il[u - 1]; il[u - 1] = ti;
                }
            }
        }
    }
    unsigned short* op = idxout + (size_t)gi * KNBR;
    #pragma unroll
    for (int t = 1; t < 21; ++t) op[t - 1] = (unsigned short)il[t];
}

// ===================== EdgeConv (fused BN + leaky + max_k) =================
template <int CIN, int RS, int COUT, int OTILE, int P>
__global__ __launch_bounds__(256) void edgeconv_kernel(
    const float* feat, const unsigned short* __restrict__ knn,
    const float* __restrict__ W, const float* __restrict__ g,
    const float* __restrict__ beta, const float* __restrict__ mu,
    const float* __restrict__ var,
    float* outb, int concat_off) {
    __shared__ float diff[P][KNBR][CIN];
    __shared__ float xil[P][CIN];
    __shared__ unsigned short kidx[P * KNBR];
    __shared__ float sl[OTILE], bl[OTILE], ml[OTILE];

    int tid = threadIdx.x;
    int h   = blockIdx.y;
    int n0  = blockIdx.x * P;                 // P divides 8192 -> same batch
    int b   = n0 >> 13;
    const float* fbase = feat + ((size_t)b << 13) * RS;

    for (int e = tid; e < P * CIN; e += 256)
        xil[e / CIN][e % CIN] = feat[(size_t)(n0 + e / CIN) * RS + e % CIN];
    for (int e = tid; e < P * KNBR; e += 256)
        kidx[e] = knn[(size_t)(n0 + e / KNBR) * KNBR + e % KNBR] & (NPTS - 1);
    for (int e = tid; e < OTILE; e += 256) {
        int o = h * OTILE + e;
        sl[e] = g[o] * rsqrtf(var[o] + 1e-5f);
        bl[e] = beta[o];
        ml[e] = mu[o];
    }
    __syncthreads();

    if (CIN % 4 == 0) {
        for (int e = tid; e < P * KNBR * (CIN / 4); e += 256) {
            int r = e / (CIN / 4), c4 = e % (CIN / 4);
            int p = r / KNBR, k = r % KNBR;
            int j = (int)kidx[r];
            float4 v = *(const float4*)(fbase + (size_t)j * RS + 4 * c4);
            diff[p][k][4 * c4 + 0] = v.x - xil[p][4 * c4 + 0];
            diff[p][k][4 * c4 + 1] = v.y - xil[p][4 * c4 + 1];
            diff[p][k][4 * c4 + 2] = v.z - xil[p][4 * c4 + 2];
            diff[p][k][4 * c4 + 3] = v.w - xil[p][4 * c4 + 3];
        }
    } else {
        for (int e = tid; e < P * KNBR * CIN; e += 256) {
            int r = e / CIN, c = e % CIN;
            int pp = r / KNBR, k = r % KNBR;
            int j = (int)kidx[r];
            diff[pp][k][c] = fbase[(size_t)j * RS + c] - xil[pp][c];
        }
    }
    __syncthreads();

    int ol = tid % OTILE, p = tid / OTILE;
    int o  = h * OTILE + ol;

    float wreg[CIN];
    #pragma unroll
    for (int c = 0; c < CIN; ++c) wreg[c] = W[(size_t)o * (2 * CIN) + c];
    float a = 0.f;
    #pragma unroll
    for (int c = 0; c < CIN; ++c) a = fmaf(wreg[c], xil[p][c], a);
    #pragma unroll
    for (int c = 0; c < CIN; ++c) wreg[c] = W[(size_t)o * (2 * CIN) + CIN + c];

    float s = sl[ol], mm = ml[ol], bb = bl[ol];
    float best = -__builtin_inff();
    for (int k = 0; k < KNBR; ++k) {
        float ac0 = a, ac1 = 0.f, ac2 = 0.f, ac3 = 0.f;
        #pragma unroll
        for (int c = 0; c < CIN; ++c) {
            float d = diff[p][k][c];
            if ((c & 3) == 0)      ac0 = fmaf(wreg[c], d, ac0);
            else if ((c & 3) == 1) ac1 = fmaf(wreg[c], d, ac1);
            else if ((c & 3) == 2) ac2 = fmaf(wreg[c], d, ac2);
            else                   ac3 = fmaf(wreg[c], d, ac3);
        }
        float acc = ((ac0 + ac1) + ac2) + ac3;
        float y = (acc - mm) * s + bb;
        y = (y >= 0.f) ? y : 0.2f * y;
        best = fmaxf(best, y);
    }
    outb[(size_t)(n0 + p) * 224 + concat_off + o] = best;
}

// ===================== conv_global: LDS-tiled GEMM + fused max =============
__global__ __launch_bounds__(256) void convglobal_kernel(
    const float* __restrict__ xcat,
    const float* __restrict__ Wg, const float* __restrict__ gg,
    const float* __restrict__ bg, const float* __restrict__ mg,
    const float* __restrict__ vg,
    float* __restrict__ partial) {
    const int KC = 56, PT = 64, OT = 64, ST = 68;   // ST: padded row stride
    __shared__ float flT[KC * ST];                  // [c][p]  15.2 KB
    __shared__ float WlT[KC * ST];                  // [c][o]  15.2 KB
    __shared__ float red[64 * 17];                  //          4.4 KB

    int tid = threadIdx.x;
    int oi  = tid & 15, pi = tid >> 4;
    int o0  = blockIdx.y * OT;
    int n0  = blockIdx.x * PT;                      // 64 | 8192 -> same batch
    int b   = n0 >> 13;
    int pchunk = blockIdx.x & 127;                  // chunk within batch

    float acc[4][4];
    #pragma unroll
    for (int u = 0; u < 4; ++u)
        #pragma unroll
        for (int v = 0; v < 4; ++v) acc[u][v] = 0.f;

    for (int kc = 0; kc < 224; kc += KC) {
        __syncthreads();
        for (int e = tid; e < PT * (KC / 4); e += 256) {
            int p = e / (KC / 4), c4 = e % (KC / 4);
            float4 v = *(const float4*)(xcat + (size_t)(n0 + p) * 224 + kc + 4 * c4);
            flT[(4 * c4 + 0) * ST + p] = v.x;
            flT[(4 * c4 + 1) * ST + p] = v.y;
            flT[(4 * c4 + 2) * ST + p] = v.z;
            flT[(4 * c4 + 3) * ST + p] = v.w;
        }
        for (int e = tid; e < OT * (KC / 4); e += 256) {
            int o = e / (KC / 4), c4 = e % (KC / 4);
            float4 v = *(const float4*)(Wg + (size_t)(o0 + o) * 224 + kc + 4 * c4);
            WlT[(4 * c4 + 0) * ST + o] = v.x;
            WlT[(4 * c4 + 1) * ST + o] = v.y;
            WlT[(4 * c4 + 2) * ST + o] = v.z;
            WlT[(4 * c4 + 3) * ST + o] = v.w;
        }
        __syncthreads();
        #pragma unroll 8
        for (int c = 0; c < KC; ++c) {
            float4 w4 = *(const float4*)(WlT + c * ST + oi * 4);
            float4 f4 = *(const float4*)(flT + c * ST + pi * 4);
            acc[0][0] = fmaf(w4.x, f4.x, acc[0][0]);
            acc[0][1] = fmaf(w4.x, f4.y, acc[0][1]);
            acc[0][2] = fmaf(w4.x, f4.z, acc[0][2]);
            acc[0][3] = fmaf(w4.x, f4.w, acc[0][3]);
            acc[1][0] = fmaf(w4.y, f4.x, acc[1][0]);
            acc[1][1] = fmaf(w4.y, f4.y, acc[1][1]);
            acc[1][2] = fmaf(w4.y, f4.z, acc[1][2]);
            acc[1][3] = fmaf(w4.y, f4.w, acc[1][3]);
            acc[2][0] = fmaf(w4.z, f4.x, acc[2][0]);
            acc[2][1] = fmaf(w4.z, f4.y, acc[2][1]);
            acc[2][2] = fmaf(w4.z, f4.z, acc[2][2]);
            acc[2][3] = fmaf(w4.z, f4.w, acc[2][3]);
            acc[3][0] = fmaf(w4.w, f4.x, acc[3][0]);
            acc[3][1] = fmaf(w4.w, f4.y, acc[3][1]);
            acc[3][2] = fmaf(w4.w, f4.z, acc[3][2]);
            acc[3][3] = fmaf(w4.w, f4.w, acc[3][3]);
        }
    }
    #pragma unroll
    for (int u = 0; u < 4; ++u) {
        int oL = oi * 4 + u, o = o0 + oL;
        float s = gg[o] * rsqrtf(vg[o] + 1e-5f);
        float mm = mg[o], bb = bg[o];
        float best = -__builtin_inff();
        #pragma unroll
        for (int v = 0; v < 4; ++v) {
            float y = (acc[u][v] - mm) * s + bb;
            y = (y >= 0.f) ? y : 0.2f * y;
            best = fmaxf(best, y);
        }
        red[oL * 17 + pi] = best;
    }
    __syncthreads();
    if (tid < 64) {
        float best = -__builtin_inff();
        #pragma unroll
        for (int q = 0; q < 16; ++q) best = fmaxf(best, red[tid * 17 + q]);
        partial[((size_t)(b * 128 + pchunk)) * 256 + o0 + tid] = best;
    }
}

__global__ void reduce_gfeat_kernel(const float* __restrict__ partial,
                                    float* __restrict__ gfeat,
                                    float* __restrict__ outg) {
    int b = blockIdx.x, o = threadIdx.x;
    float best = -__builtin_inff();
    for (int ch = 0; ch < 128; ++ch)
        best = fmaxf(best, partial[((size_t)b * 128 + ch) * 256 + o]);
    gfeat[b * 256 + o] = best;
    outg[b * 256 + o]  = best;
}

// ===================== heads (per-batch block) =============================
__global__ __launch_bounds__(256) void heads_kernel(
    const float* __restrict__ gfeat,
    const float* __restrict__ Wv1, const float* __restrict__ bv1,
    const float* __restrict__ Wv2, const float* __restrict__ bv2,
    const float* __restrict__ Wq1, const float* __restrict__ bq1,
    const float* __restrict__ Wq2, const float* __restrict__ bq2,
    float* __restrict__ out) {
    int b = blockIdx.x, t = threadIdx.x;
    __shared__ float gf[256], h[512], q[64];
    gf[t] = gfeat[b * 256 + t];
    __syncthreads();
    for (int r = t; r < 512; r += 256) {
        float acc = bv1[r];
        for (int c = 0; c < 256; ++c) acc = fmaf(Wv1[r * 256 + c], gf[c], acc);
        h[r] = fmaxf(acc, 0.f);
    }
    __syncthreads();
    if (t < 192) {
        float acc = bv2[t];
        for (int c = 0; c < 512; ++c) acc = fmaf(Wv2[t * 512 + c], h[c], acc);
        out[b * 192 + t] = acc;               // vertex_coords
    } else {
        int r = t - 192;
        if (r < 64) {
            float acc = bq1[r];
            for (int c = 0; c < 256; ++c) acc = fmaf(Wq1[r * 256 + c], gf[c], acc);
            q[r] = fmaxf(acc, 0.f);
        }
    }
    __syncthreads();
    if (t == 0) {
        float acc = bq2[0];
        for (int c = 0; c < 64; ++c) acc = fmaf(Wq2[c], q[c], acc);
        float nv = 1.0f / (1.0f + expf(-acc));
        out[772 + b] = nv;                                       // nvs
        float num = fminf(fmaxf(rintf(nv * 64.0f), 1.0f), 64.0f);
        out[768 + b] = num;                                      // num_vertices
    }
}

// ============================== launch =====================================
extern "C" void kernel_launch(void* const* d_in, const int* in_sizes, int n_in,
                              void* d_out, int out_size, void* d_ws, size_t ws_size,
                              hipStream_t stream) {
    (void)in_sizes; (void)n_in; (void)out_size; (void)ws_size;
    const float* x   = (const float*)d_in[0];
    const float* W1  = (const float*)d_in[1];
    const float* g1  = (const float*)d_in[2];
    const float* b1  = (const float*)d_in[3];
    const float* m1  = (const float*)d_in[4];
    const float* v1  = (const float*)d_in[5];
    const float* W2  = (const float*)d_in[6];
    const float* g2  = (const float*)d_in[7];
    const float* b2  = (const float*)d_in[8];
    const float* m2  = (const float*)d_in[9];
    const float* v2  = (const float*)d_in[10];
    const float* W3  = (const float*)d_in[11];
    const float* g3  = (const float*)d_in[12];
    const float* b3  = (const float*)d_in[13];
    const float* m3  = (const float*)d_in[14];
    const float* v3  = (const float*)d_in[15];
    const float* Wg  = (const float*)d_in[16];
    const float* gg  = (const float*)d_in[17];
    const float* bg  = (const float*)d_in[18];
    const float* mg  = (const float*)d_in[19];
    const float* vg  = (const float*)d_in[20];
    const float* Wv1 = (const float*)d_in[21];
    const float* bv1 = (const float*)d_in[22];
    const float* Wv2 = (const float*)d_in[23];
    const float* bv2 = (const float*)d_in[24];
    const float* Wq1 = (const float*)d_in[25];
    const float* bq1 = (const float*)d_in[26];
    const float* Wq2 = (const float*)d_in[27];
    const float* bq2 = (const float*)d_in[28];

    float* out  = (float*)d_out;
    float* xcat = out + 1800;                    // f32 [4,8192,224]
    char* ws = (char*)d_ws;
    const int ROWS = BATCH * NPTS;   // 32768

    // ws layout (1,310,720 B; part/gft alias idx AFTER it is dead):
    unsigned short* idx  = (unsigned short*)(ws);        // [32768,20] u16
    float*          part = (float*)(ws);                 // [512,256] f32 (alias)
    float*          gft  = (float*)(ws + 524288);        // [4,256]   f32 (alias)

    // ---- EdgeConv 1: 5 -> 32
    knn_part<5, 5, 8, 128, 8><<<dim3(ROWS / 128, 8), 128, 0, stream>>>(x, xcat);
    knn_merge<5, 5, 8><<<ROWS / 256, 256, 0, stream>>>(x, xcat, idx);
    edgeconv_kernel<5, 5, 32, 32, 8>
        <<<dim3(ROWS / 8, 1), 256, 0, stream>>>(x, idx, W1, g1, b1, m1, v1, xcat, 0);

    // ---- EdgeConv 2: 32 -> 64 (features from xcat[:,0:32))
    knn_part<32, 224, 8, 128, 8><<<dim3(ROWS / 128, 8), 128, 0, stream>>>(xcat, xcat);
    knn_merge<32, 224, 8><<<ROWS / 256, 256, 0, stream>>>(xcat, xcat, idx);
    edgeconv_kernel<32, 224, 64, 64, 4>
        <<<dim3(ROWS / 4, 1), 256, 0, stream>>>(xcat, idx, W2, g2, b2, m2, v2, xcat, 32);

    // ---- EdgeConv 3: 64 -> 128 (features from xcat[:,32:96))
    knn_part<64, 224, 8, 64, 8><<<dim3(ROWS / 128, 8), 128, 0, stream>>>(xcat + 32, xcat);
    knn_merge<64, 224, 8><<<ROWS / 256, 256, 0, stream>>>(xcat + 32, xcat, idx);
    edgeconv_kernel<64, 224, 128, 64, 4>
        <<<dim3(ROWS / 4, 2), 256, 0, stream>>>(xcat + 32, idx, W3, g3, b3, m3, v3, xcat, 96);

    // ---- conv_global (224->256) + max over N  (idx dead; part aliases it)
    convglobal_kernel<<<dim3(ROWS / 64, 4), 256, 0, stream>>>(
        xcat, Wg, gg, bg, mg, vg, part);
    reduce_gfeat_kernel<<<BATCH, 256, 0, stream>>>(part, gft, out + 776);

    // ---- heads
    heads_kernel<<<BATCH, 256, 0, stream>>>(
        gft, Wv1, bv1, Wv2, bv2, Wq1, bq1, Wq2, bq2, out);
}